// Round 12
// baseline (3561.105 us; speedup 1.0000x reference)
//
#include <hip/hip_runtime.h>
#include <hip/hip_bf16.h>
#include <math.h>

typedef __bf16 bf16x8 __attribute__((ext_vector_type(8)));
typedef float f32x4 __attribute__((ext_vector_type(4)));
typedef unsigned short u16x8 __attribute__((ext_vector_type(8)));

#define VMW(N) asm volatile("s_waitcnt vmcnt(" #N ")" ::: "memory")
#define LGKM0  asm volatile("s_waitcnt lgkmcnt(0)" ::: "memory")
#define CFENCE asm volatile("" ::: "memory")

__device__ inline unsigned short f2b(float f) {
  union { float f; unsigned u; } v; v.f = f;
  unsigned u = v.u;
  return (unsigned short)((u + 0x7fffu + ((u >> 16) & 1u)) >> 16);
}
__device__ inline float b2f(unsigned short s) {
  union { unsigned u; float f; } v; v.u = ((unsigned)s) << 16;
  return v.f;
}
__device__ inline float sigm(float x) { return 1.f / (1.f + __expf(-x)); }
__device__ inline float tanh_f(float x) {
  float e = __expf(2.f * x);
  return 1.f - 2.f / (e + 1.f);
}
// cached global->LDS 16B
__device__ inline void gll16(const unsigned short* g, unsigned short* l) {
  __builtin_amdgcn_global_load_lds(
      (const __attribute__((address_space(1))) void*)g,
      (__attribute__((address_space(3))) void*)l, 16, 0, 0);
}
__device__ inline unsigned long long al64(const unsigned short* p) {
  return __hip_atomic_load((const unsigned long long*)p, __ATOMIC_RELAXED,
                           __HIP_MEMORY_SCOPE_AGENT);
}
__device__ inline void as64(unsigned short* p, unsigned long long v) {
  __hip_atomic_store((unsigned long long*)p, v, __ATOMIC_RELAXED,
                     __HIP_MEMORY_SCOPE_AGENT);
}
__device__ inline bf16x8 pack16(unsigned long long a, unsigned long long b) {
  union { unsigned long long u[2]; bf16x8 v; } c;
  c.u[0] = a; c.u[1] = b;
  return c.v;
}

// -------------------- prep: weights->bf16, h init --------------------
__global__ __launch_bounds__(256) void prep_kernel(
    const float* __restrict__ Wih, const float* __restrict__ Whh,
    const float* __restrict__ c, unsigned short* __restrict__ Wihb,
    unsigned short* __restrict__ Whhb, unsigned short* __restrict__ hbf,
    float* __restrict__ h32, long nW, long nH)
{
  long stride = (long)gridDim.x * blockDim.x;
  long t0 = (long)blockIdx.x * blockDim.x + threadIdx.x;
  for (long i = t0; i < nW; i += stride) {
    Wihb[i] = f2b(Wih[i]);
    Whhb[i] = f2b(Whh[i]);
  }
  for (long i = t0; i < nH; i += stride) {
    float v = c[i];
    h32[i] = v;
    hbf[i] = f2b(v);
  }
}

// ---- reorder rows: row' = (g6*3+g)*64+elo  <-  row = g*E + g6*64 + elo ----
__global__ __launch_bounds__(256) void reorder_kernel(
    const unsigned short* __restrict__ Wihb, const unsigned short* __restrict__ Whhb,
    const float* __restrict__ bih, const float* __restrict__ bhh,
    unsigned short* __restrict__ Wihp, unsigned short* __restrict__ Whhp,
    float* __restrict__ bihp, float* __restrict__ bhhp, int E)
{
  int N3 = 3 * E;
  long total = (long)N3 * E;
  long stride = (long)gridDim.x * blockDim.x;
  long t0 = (long)blockIdx.x * blockDim.x + threadIdx.x;
  for (long i = t0; i < total; i += stride) {
    int rp = (int)(i / E);
    int col = (int)(i - (long)rp * E);
    int g6 = rp / 192, rem = rp - g6 * 192;
    int g = rem >> 6, elo = rem & 63;
    long src = ((long)g * E + g6 * 64 + elo) * E + col;
    Wihp[i] = Wihb[src];
    Whhp[i] = Whhb[src];
  }
  for (long i = t0; i < N3; i += stride) {
    int rp = (int)i;
    int g6 = rp / 192, rem = rp - g6 * 192;
    int g = rem >> 6, elo = rem & 63;
    bihp[i] = bih[(long)g * E + g6 * 64 + elo];
    bhhp[i] = bhh[(long)g * E + g6 * 64 + elo];
  }
}

// -------------------- transpose x (B,E,K) -> XS (K,B,E) bf16 ----------
__global__ __launch_bounds__(256) void transpose_x(
    const float* __restrict__ x, unsigned short* __restrict__ XS,
    int B, int E, int K)
{
  __shared__ float T[64][65];
  int e0 = blockIdx.x * 64;
  int b = blockIdx.y;
  int t = threadIdx.x;
  const float* xb = x + ((long)b * E + e0) * K;
#pragma unroll
  for (int i = 0; i < 4; ++i) {
    int cidx = i * 256 + t;
    int e = cidx >> 4;
    int f4 = cidx & 15;
    float4 v = *(const float4*)(xb + (long)e * K + f4 * 4);
    T[e][f4 * 4 + 0] = v.x;
    T[e][f4 * 4 + 1] = v.y;
    T[e][f4 * 4 + 2] = v.z;
    T[e][f4 * 4 + 3] = v.w;
  }
  __syncthreads();
#pragma unroll
  for (int i = 0; i < 16; ++i) {
    int cidx = i * 256 + t;
    int k = cidx >> 6;
    int e = cidx & 63;
    if (k < K - 1)
      XS[((long)(k + 1) * B + b) * E + e0 + e] = f2b(T[e][k]);
  }
}

// ---------- gemm256: C(M,N)=A(M,K)@Bw(N,K)^T + bias, bf16 out --------
__global__ __launch_bounds__(512, 1)
void gemm256(const unsigned short* __restrict__ A,
             const unsigned short* __restrict__ Bw,
             const float* __restrict__ bias,
             unsigned short* __restrict__ Cb,
             int M, int N, int K)
{
  __shared__ __align__(16) unsigned short sm[3 * 24576];  // 144 KB

  int nwg = gridDim.x * gridDim.y;
  int wg = blockIdx.y * gridDim.x + blockIdx.x;
  if ((nwg & 7) == 0) { int ch = nwg >> 3; wg = (wg & 7) * ch + (wg >> 3); }
  int tx = wg % gridDim.x;   // N tile (256)
  int ty = wg / gridDim.x;   // M tile (128)

  const int tid = threadIdx.x;
  const int lane = tid & 63;
  const int wave = tid >> 6;
  const int wm = wave >> 2;
  const int wn = wave & 3;
  const int q = lane >> 4;
  const int l15 = lane & 15;

  const long a_base = (long)ty * 128 * K;
  const long b_base = (long)tx * 256 * K;

  long a_src[2]; int a_dst[2];
#pragma unroll
  for (int i = 0; i < 2; ++i) {
    int c = i * 512 + tid;
    int row = c >> 3;
    int g8 = (c & 7) ^ (row & 7);
    a_src[i] = a_base + (long)row * K + g8 * 8;
    a_dst[i] = c * 8;
  }
  long b_src[4]; int b_dst[4];
#pragma unroll
  for (int i = 0; i < 4; ++i) {
    int c = i * 512 + tid;
    int row = c >> 3;
    int g8 = (c & 7) ^ (row & 7);
    b_src[i] = b_base + (long)row * K + g8 * 8;
    b_dst[i] = c * 8;
  }

  int a_ro[4], b_ro[4];
#pragma unroll
  for (int mi = 0; mi < 4; ++mi) {
    int lr = wm * 64 + mi * 16 + l15;
    a_ro[mi] = lr * 64;
  }
#pragma unroll
  for (int ni = 0; ni < 4; ++ni) {
    int col = wn * 64 + ni * 16 + l15;
    b_ro[ni] = col * 64;
  }

  f32x4 acc[4][4] = {};

  const int NT = K >> 6;
#pragma unroll
  for (int t = 0; t < 2; ++t) {
    unsigned short* As = sm + t * 24576;
    unsigned short* Bs = As + 8192;
#pragma unroll
    for (int i = 0; i < 2; ++i) gll16(A + a_src[i] + t * 64, As + a_dst[i]);
#pragma unroll
    for (int i = 0; i < 4; ++i) gll16(Bw + b_src[i] + t * 64, Bs + b_dst[i]);
  }

  for (int kt = 0; kt < NT; ++kt) {
    if (kt >= NT - 2) VMW(0); else VMW(6);
    __builtin_amdgcn_s_barrier();
    CFENCE;
    const unsigned short* As = sm + (kt % 3) * 24576;
    const unsigned short* Bs = As + 8192;
    unsigned short* As2 = sm + ((kt + 2) % 3) * 24576;
    unsigned short* Bs2 = As2 + 8192;
    const bool st = (kt + 2 < NT);
    const int ko = (kt + 2) * 64;

    if (st) {
      gll16(A + a_src[0] + ko, As2 + a_dst[0]);
      gll16(A + a_src[1] + ko, As2 + a_dst[1]);
      gll16(Bw + b_src[0] + ko, Bs2 + b_dst[0]);
    }
    {
      const int c8 = q;
      bf16x8 af[4], bf_[4];
#pragma unroll
      for (int mi = 0; mi < 4; ++mi) {
        int lr = wm * 64 + mi * 16 + l15;
        af[mi] = *(const bf16x8*)&As[a_ro[mi] + ((c8 ^ (lr & 7)) << 3)];
      }
#pragma unroll
      for (int ni = 0; ni < 4; ++ni) {
        int col = wn * 64 + ni * 16 + l15;
        bf_[ni] = *(const bf16x8*)&Bs[b_ro[ni] + ((c8 ^ (col & 7)) << 3)];
      }
      __builtin_amdgcn_s_setprio(1);
#pragma unroll
      for (int mi = 0; mi < 4; ++mi)
#pragma unroll
        for (int ni = 0; ni < 4; ++ni)
          acc[mi][ni] = __builtin_amdgcn_mfma_f32_16x16x32_bf16(
              af[mi], bf_[ni], acc[mi][ni], 0, 0, 0);
      __builtin_amdgcn_s_setprio(0);
    }
    LGKM0;
    __builtin_amdgcn_s_barrier();
    CFENCE;
    if (st) {
      gll16(Bw + b_src[1] + ko, Bs2 + b_dst[1]);
      gll16(Bw + b_src[2] + ko, Bs2 + b_dst[2]);
      gll16(Bw + b_src[3] + ko, Bs2 + b_dst[3]);
    }
    {
      const int c8 = 4 + q;
      bf16x8 af[4], bf_[4];
#pragma unroll
      for (int mi = 0; mi < 4; ++mi) {
        int lr = wm * 64 + mi * 16 + l15;
        af[mi] = *(const bf16x8*)&As[a_ro[mi] + ((c8 ^ (lr & 7)) << 3)];
      }
#pragma unroll
      for (int ni = 0; ni < 4; ++ni) {
        int col = wn * 64 + ni * 16 + l15;
        bf_[ni] = *(const bf16x8*)&Bs[b_ro[ni] + ((c8 ^ (col & 7)) << 3)];
      }
      __builtin_amdgcn_s_setprio(1);
#pragma unroll
      for (int mi = 0; mi < 4; ++mi)
#pragma unroll
        for (int ni = 0; ni < 4; ++ni)
          acc[mi][ni] = __builtin_amdgcn_mfma_f32_16x16x32_bf16(
              af[mi], bf_[ni], acc[mi][ni], 0, 0, 0);
      __builtin_amdgcn_s_setprio(0);
    }
    LGKM0;
  }

  long crow0 = (long)ty * 128 + wm * 64;
  long ccol0 = (long)tx * 256 + wn * 64;
#pragma unroll
  for (int mi = 0; mi < 4; ++mi) {
#pragma unroll
    for (int ni = 0; ni < 4; ++ni) {
      long col = ccol0 + ni * 16 + l15;
      float bv = bias[col];
#pragma unroll
      for (int j = 0; j < 4; ++j) {
        long row = crow0 + mi * 16 + (q << 2) + j;
        Cb[row * N + col] = f2b(acc[mi][ni][j] + bv);
      }
    }
  }
}

// -------------------- GEMM (fallback path): 128x128 m97-style ---------
#define BM 128
#define BN 128
#define BKS 64

template<int OUTBF>
__global__ __launch_bounds__(256)
void gemm_bt(const unsigned short* __restrict__ A,
             const unsigned short* __restrict__ Bw,
             const float* __restrict__ bias,
             float* __restrict__ Cf, unsigned short* __restrict__ Cb,
             int M, int N, int K)
{
  __shared__ __align__(16) unsigned short As[BM * BKS];
  __shared__ __align__(16) unsigned short Bs[BN * BKS];

  int nwg = gridDim.x * gridDim.y;
  int wg = blockIdx.y * gridDim.x + blockIdx.x;
  if ((nwg & 7) == 0) { int ch = nwg >> 3; wg = (wg & 7) * ch + (wg >> 3); }
  int tx = wg % gridDim.x;
  int ty = wg / gridDim.x;

  const int tid = threadIdx.x;
  const int lane = tid & 63;
  const int wave = tid >> 6;
  const int wr = wave >> 1, wc = wave & 1;

  f32x4 acc[4][4] = {};

  const long a_base = (long)ty * BM * K;
  const long b_base = (long)tx * BN * K;

  for (int kt = 0; kt < K; kt += BKS) {
    __syncthreads();
#pragma unroll
    for (int i = 0; i < 4; ++i) {
      int c = i * 256 + tid;
      int row = c >> 3, sc = c & 7;
      int gcol8 = sc ^ (row & 7);
      const unsigned short* ga = A + a_base + (long)row * K + kt + gcol8 * 8;
      const unsigned short* gb = Bw + b_base + (long)row * K + kt + gcol8 * 8;
      int cbase = (i * 256 + wave * 64) * 8;
      gll16(ga, &As[cbase]);
      gll16(gb, &Bs[cbase]);
    }
    __syncthreads();
#pragma unroll
    for (int kk = 0; kk < BKS; kk += 32) {
      int kidx = kk + ((lane >> 4) << 3);
      int c8 = kidx >> 3;
      bf16x8 af[4], bfv[4];
#pragma unroll
      for (int m = 0; m < 4; ++m) {
        int row = wr * 64 + m * 16 + (lane & 15);
        af[m] = *(const bf16x8*)&As[row * BKS + ((c8 ^ (row & 7)) << 3)];
      }
#pragma unroll
      for (int n = 0; n < 4; ++n) {
        int col = wc * 64 + n * 16 + (lane & 15);
        bfv[n] = *(const bf16x8*)&Bs[col * BKS + ((c8 ^ (col & 7)) << 3)];
      }
#pragma unroll
      for (int m = 0; m < 4; ++m)
#pragma unroll
        for (int n = 0; n < 4; ++n)
          acc[m][n] = __builtin_amdgcn_mfma_f32_16x16x32_bf16(
              af[m], bfv[n], acc[m][n], 0, 0, 0);
    }
  }

  long crow0 = (long)ty * BM + wr * 64;
  long ccol0 = (long)tx * BN + wc * 64;
#pragma unroll
  for (int m = 0; m < 4; ++m) {
#pragma unroll
    for (int n = 0; n < 4; ++n) {
      long col = ccol0 + n * 16 + (lane & 15);
      float bv = bias[col];
#pragma unroll
      for (int j = 0; j < 4; ++j) {
        long row = crow0 + m * 16 + ((lane >> 4) << 2) + j;
        float v = acc[m][n][j] + bv;
        if (OUTBF) Cb[row * N + col] = f2b(v);
        else       Cf[row * N + col] = v;
      }
    }
  }
}

// -------------------- persistent fused recurrence v8 ------------------
// Barrier-free, LDS-free kt loop: each wave streams its MFMA fragments
// straight from global to registers (A: coherent al64 pairs, depth-3 ring;
// B: plain bf16x8 loads from the L2-resident panel, depth-2 ring), fully
// unrolled with static register sets. NO s_barrier, NO ds ops, NO manual
// vmcnt in the loop -- 8 self-paced waves/CU provide the overlap (m114).
// GI staged via DMA at prolog; one __syncthreads before gates drains it.
// Reduce / gates / stores / flag barrier identical to v4 (5x verified).
__global__ __launch_bounds__(512, 2)
void gru_rec8(const unsigned short* __restrict__ GI,
              const unsigned short* __restrict__ Whp,
              const float* __restrict__ bhp,
              const unsigned short* __restrict__ h0,
              unsigned short* __restrict__ hbuf0,
              unsigned short* __restrict__ hbuf1,
              unsigned short* __restrict__ Y,
              unsigned int* __restrict__ bar,
              int B, int E, int K, int net)
{
  __shared__ __align__(16) unsigned short GIs[12288];   // 24 KB (64x192)
  __shared__ __align__(16) unsigned short Ys[64 * 72];  // 9 KB persistent h
  __shared__ float Red[4 * 64 * 49];                    // 49 KB K-split

  const int N3 = 3 * E;
  const int e6 = blockIdx.x;           // e6%8 -> XCD pinning of Whh panel
  const int bt = blockIdx.y;
  const int b0 = bt << 6;
  const int ec0 = e6 * 192;
  const int ecol0 = e6 << 6;
  const int tid = threadIdx.x;
  const int lane = tid & 63;
  const int w = tid >> 6;
  const int ew = w >> 1;               // e-col group (16 cols)
  const int kw = w & 1;                // K-half of each 64-k tile
  const int q = lane >> 4;
  const int l15 = lane & 15;
  const int el = (ew << 4) + l15;

  // GI staging (DMA, cached): 3 chunks/thread/step -> GIs[row*192 + col]
  long gi_off[3]; int gi_dst[3];
#pragma unroll
  for (int i = 0; i < 3; ++i) {
    int c = i * 512 + tid;
    int row = c / 24, cc = c - row * 24;
    gi_off[i] = (long)(b0 + row) * N3 + ec0 + cc * 8;
    gi_dst[i] = c * 8;
  }

  // per-lane fragment base offsets (halfword units), advance by kt*64
  long a_rp[4];
#pragma unroll
  for (int m = 0; m < 4; ++m)
    a_rp[m] = (long)(b0 + m * 16 + l15) * E + kw * 32 + q * 8;
  const unsigned short* wp[3];
#pragma unroll
  for (int g = 0; g < 3; ++g)
    wp[g] = Whp + (long)(ec0 + g * 64 + el) * E + kw * 32 + q * 8;

  const float bh0 = bhp[ec0 + el];
  const float bh1 = bhp[ec0 + 64 + el];
  const float bh2 = bhp[ec0 + 128 + el];

  // Ys preload: persistent per-WG h cache (kw==0 lanes own gate outputs)
  if (kw == 0) {
#pragma unroll
    for (int m = 0; m < 4; ++m)
#pragma unroll
      for (int j = 0; j < 4; ++j) {
        int row = m * 16 + q * 4 + j;
        Ys[row * 72 + el] = h0[(long)(b0 + row) * E + ecol0 + el];
      }
  }
  __syncthreads();

  for (int k = 0; k < K; ++k) {
    const unsigned short* hprev = (k & 1) ? hbuf1 : hbuf0;
    unsigned short* hnext = (k & 1) ? hbuf0 : hbuf1;
    const unsigned short* GIk = GI + (long)k * B * N3;

    // GI DMA (consumed at gates; a whole step to land)
#pragma unroll
    for (int i = 0; i < 3; ++i) gll16(GIk + gi_off[i], GIs + gi_dst[i]);

    // ---- register prologue: A tiles 0..2 (coherent), B tiles 0..1 ----
    unsigned long long Au[3][4][2];
    bf16x8 Bv[2][3];
#pragma unroll
    for (int t = 0; t < 3; ++t)
#pragma unroll
      for (int m = 0; m < 4; ++m) {
        const unsigned short* p = hprev + a_rp[m] + t * 64;
        Au[t][m][0] = al64(p);
        Au[t][m][1] = al64(p + 4);
      }
#pragma unroll
    for (int t = 0; t < 2; ++t)
#pragma unroll
      for (int g = 0; g < 3; ++g)
        Bv[t][g] = *(const bf16x8*)(wp[g] + t * 64);

    f32x4 acc[4][3];
#pragma unroll
    for (int m = 0; m < 4; ++m)
#pragma unroll
      for (int g = 0; g < 3; ++g)
        acc[m][g] = (f32x4){0.f, 0.f, 0.f, 0.f};

    // ---- barrier-free kt loop: issue next, compute current ----
#pragma unroll
    for (int kt = 0; kt < 16; ++kt) {
      const int sa = kt % 3;
      const int sb = kt & 1;
      bf16x8 af[4];
#pragma unroll
      for (int m = 0; m < 4; ++m)
        af[m] = pack16(Au[sa][m][0], Au[sa][m][1]);
      bf16x8 bg0 = Bv[sb][0], bg1 = Bv[sb][1], bg2 = Bv[sb][2];

      if (kt + 3 < 16) {
#pragma unroll
        for (int m = 0; m < 4; ++m) {
          const unsigned short* p = hprev + a_rp[m] + (kt + 3) * 64;
          Au[sa][m][0] = al64(p);
          Au[sa][m][1] = al64(p + 4);
        }
      }
      if (kt + 2 < 16) {
#pragma unroll
        for (int g = 0; g < 3; ++g)
          Bv[sb][g] = *(const bf16x8*)(wp[g] + (kt + 2) * 64);
      }

      __builtin_amdgcn_s_setprio(1);
#pragma unroll
      for (int m = 0; m < 4; ++m) {
        acc[m][0] = __builtin_amdgcn_mfma_f32_16x16x32_bf16(af[m], bg0, acc[m][0], 0, 0, 0);
        acc[m][1] = __builtin_amdgcn_mfma_f32_16x16x32_bf16(af[m], bg1, acc[m][1], 0, 0, 0);
        acc[m][2] = __builtin_amdgcn_mfma_f32_16x16x32_bf16(af[m], bg2, acc[m][2], 0, 0, 0);
      }
      __builtin_amdgcn_s_setprio(0);
    }

    // ---- K-split reduce + fused gates (v4 verbatim) ----
    __syncthreads();   // joins waves; drains GI DMA (vmcnt(0) per wave)
    float* rp = &Red[((ew << 6) + lane) * 49];
    if (kw == 1) {
#pragma unroll
      for (int m = 0; m < 4; ++m)
#pragma unroll
        for (int g = 0; g < 3; ++g)
#pragma unroll
          for (int cc = 0; cc < 4; ++cc)
            rp[(m * 3 + g) * 4 + cc] = acc[m][g][cc];
    }
    __syncthreads();
    if (kw == 0) {
#pragma unroll
      for (int m = 0; m < 4; ++m) {
#pragma unroll
        for (int j = 0; j < 4; ++j) {
          int row = m * 16 + q * 4 + j;
          float ghr = acc[m][0][j] + rp[(m * 3 + 0) * 4 + j];
          float ghz = acc[m][1][j] + rp[(m * 3 + 1) * 4 + j];
          float ghn = acc[m][2][j] + rp[(m * 3 + 2) * 4 + j];
          float gr = b2f(GIs[row * 192 + el]);
          float gz = b2f(GIs[row * 192 + 64 + el]);
          float gn = b2f(GIs[row * 192 + 128 + el]);
          float hu = b2f(Ys[row * 72 + el]);
          float r = sigm(gr + ghr + bh0);
          float z = sigm(gz + ghz + bh1);
          float n = tanh_f(gn + r * (ghn + bh2));
          float hv = (1.f - z) * n + z * hu;
          Ys[row * 72 + el] = f2b(hv);
        }
      }
    }
    __syncthreads();
    // ---- write-out: h_next coherent atomics, Y plain stores ----
    {
      int row = tid >> 3, cc = tid & 7;
      u16x8 v = *(const u16x8*)&Ys[row * 72 + cc * 8];
      unsigned* pv = (unsigned*)&v;
      unsigned long long s0 = ((unsigned long long)pv[1] << 32) | pv[0];
      unsigned long long s1 = ((unsigned long long)pv[3] << 32) | pv[2];
      unsigned short* hp = hnext + (long)(b0 + row) * E + ecol0 + cc * 8;
      as64(hp, s0);
      as64(hp + 4, s1);
      *(u16x8*)(Y + ((long)k * B + b0 + row) * E + ecol0 + cc * 8) = v;
    }
    // ---- per-bt flag barrier ----
    if (k + 1 < K) {
      __syncthreads();
      if (tid == 0) {
        __hip_atomic_fetch_add(&bar[bt * 64], 1u, __ATOMIC_RELAXED,
                               __HIP_MEMORY_SCOPE_AGENT);
        unsigned target = (unsigned)(k + 1) * (unsigned)net;
        while (__hip_atomic_load(&bar[bt * 64], __ATOMIC_RELAXED,
                                 __HIP_MEMORY_SCOPE_AGENT) < target)
          __builtin_amdgcn_s_sleep(1);
      }
      __syncthreads();
    }
  }
}

// -------------------- pointwise GRU gates (fallback path) -------------
template<int YMODE>
__global__ __launch_bounds__(256)
void gru_pointwise(const unsigned short* __restrict__ GIk,
                   const float* __restrict__ gh,
                   float* __restrict__ h, unsigned short* __restrict__ hbf,
                   unsigned short* __restrict__ Yb,
                   float* __restrict__ out, int k, int B, int E, int K)
{
  long i4 = ((long)blockIdx.x * blockDim.x + threadIdx.x) * 4;
  if (i4 >= (long)B * E) return;
  long b = i4 / E;
  long e = i4 - b * E;
  long g0 = b * 3 * E + e;
  ushort4 ir = *(const ushort4*)(GIk + g0);
  ushort4 iz = *(const ushort4*)(GIk + g0 + E);
  ushort4 in4 = *(const ushort4*)(GIk + g0 + 2 * E);
  float4 hr = *(const float4*)(gh + g0);
  float4 hz = *(const float4*)(gh + g0 + E);
  float4 hn = *(const float4*)(gh + g0 + 2 * E);
  float4 hv = *(const float4*)(h + i4);

  float irf[4] = { b2f(ir.x), b2f(ir.y), b2f(ir.z), b2f(ir.w) };
  float izf[4] = { b2f(iz.x), b2f(iz.y), b2f(iz.z), b2f(iz.w) };
  float inf_[4] = { b2f(in4.x), b2f(in4.y), b2f(in4.z), b2f(in4.w) };
  float hrf[4] = { hr.x, hr.y, hr.z, hr.w };
  float hzf[4] = { hz.x, hz.y, hz.z, hz.w };
  float hnf[4] = { hn.x, hn.y, hn.z, hn.w };
  float hvf[4] = { hv.x, hv.y, hv.z, hv.w };
  float hnew[4];
#pragma unroll
  for (int j = 0; j < 4; ++j) {
    float r = sigm(irf[j] + hrf[j]);
    float z = sigm(izf[j] + hzf[j]);
    float n = tanh_f(inf_[j] + r * hnf[j]);
    hnew[j] = (1.f - z) * n + z * hvf[j];
  }
  *(float4*)(h + i4) = make_float4(hnew[0], hnew[1], hnew[2], hnew[3]);
  ushort4 hb = make_ushort4(f2b(hnew[0]), f2b(hnew[1]), f2b(hnew[2]), f2b(hnew[3]));
  *(ushort4*)(hbf + i4) = hb;
  if (YMODE == 1) {
    *(ushort4*)(Yb + ((long)k * B + b) * E + e) = hb;
  } else {
    float* o = out + (b * E + e) * K + k;
    o[0] = hnew[0]; o[K] = hnew[1]; o[2 * K] = hnew[2]; o[3 * K] = hnew[3];
  }
}

// -------------------- transpose Y (K,B,E) bf16 -> out (B,E,K) fp32 ----
__global__ __launch_bounds__(256)
void transpose_y(const unsigned short* __restrict__ Yv, float* __restrict__ out,
                 int B, int E, int K)
{
  __shared__ float T[64][65];
  int e0 = blockIdx.x * 64;
  int b = blockIdx.y;
  int t = threadIdx.x;
#pragma unroll
  for (int i = 0; i < 4; ++i) {
    int c = i * 256 + t;
    int k = c >> 4, f4 = c & 15;
    long off = ((long)k * B + b) * E + e0 + f4 * 4;
    ushort4 v = *(const ushort4*)(Yv + off);
    T[k][f4 * 4 + 0] = b2f(v.x); T[k][f4 * 4 + 1] = b2f(v.y);
    T[k][f4 * 4 + 2] = b2f(v.z); T[k][f4 * 4 + 3] = b2f(v.w);
  }
  __syncthreads();
#pragma unroll
  for (int i = 0; i < 4; ++i) {
    int c = i * 256 + t;
    int e = c >> 4, f4k = c & 15;
    float4 w;
    w.x = T[f4k * 4 + 0][e];
    w.y = T[f4k * 4 + 1][e];
    w.z = T[f4k * 4 + 2][e];
    w.w = T[f4k * 4 + 3][e];
    *(float4*)(out + ((long)b * E + e0 + e) * K + f4k * 4) = w;
  }
}

// -------------------- host launch -------------------------------------
extern "C" void kernel_launch(void* const* d_in, const int* in_sizes, int n_in,
                              void* d_out, int out_size, void* d_ws, size_t ws_size,
                              hipStream_t stream)
{
  const float* c   = (const float*)d_in[0];
  const float* x   = (const float*)d_in[1];
  const float* Wih = (const float*)d_in[2];
  const float* Whh = (const float*)d_in[3];
  const float* bih = (const float*)d_in[4];
  const float* bhh = (const float*)d_in[5];
  float* out = (float*)d_out;

  long BE = in_sizes[0];
  int E = (int)(sqrtf((float)(in_sizes[2] / 3)) + 0.5f);
  int B = (int)(BE / E);
  int K = (int)(in_sizes[1] / BE);
  int N3 = 3 * E;
  long M_GI = (long)K * B;

  char* w = (char*)d_ws;
  size_t used = 0;
  auto alloc = [&](size_t bytes) -> char* {
    char* p = w + used;
    used += (bytes + 255) & ~(size_t)255;
    return p;
  };
  unsigned short* Wihb  = (unsigned short*)alloc((size_t)N3 * E * 2);
  unsigned short* Whhb  = (unsigned short*)alloc((size_t)N3 * E * 2);
  unsigned short* hb0   = (unsigned short*)alloc((size_t)B * E * 2);
  float* h32            = (float*)alloc((size_t)B * E * 4);
  float* gh             = (float*)alloc((size_t)B * N3 * 4);
  unsigned short* GIstep= (unsigned short*)alloc((size_t)B * N3 * 2);
  unsigned short* XS    = (unsigned short*)alloc((size_t)K * B * E * 2);

  size_t rem = (ws_size > used) ? ws_size - used : 0;
  size_t szW   = (((size_t)N3 * E * 2) + 255) & ~(size_t)255;
  size_t szB3  = (((size_t)N3 * 4) + 255) & ~(size_t)255;
  size_t szHb1 = (((size_t)B * E * 2) + 255) & ~(size_t)255;
  size_t szGI  = (((size_t)K * B * N3 * 2) + 255) & ~(size_t)255;
  size_t szY   = (((size_t)K * B * E * 2) + 255) & ~(size_t)255;
  int nbt = B / 64, net = E / 64;
  size_t szBar = ((size_t)nbt * 64 * 4 + 255) & ~(size_t)255;

  bool canFused = (B == 1024) && (E == 1024) &&
                  (rem >= 2 * szW + 2 * szB3 + szHb1 + szGI + szY + szBar);

  long nW = (long)N3 * E;
  prep_kernel<<<dim3(2048), dim3(256), 0, stream>>>(Wih, Whh, c, Wihb, Whhb,
                                                    hb0, h32, nW, BE);
  hipMemsetAsync(XS, 0, (size_t)B * E * 2, stream);
  transpose_x<<<dim3(E / 64, B), dim3(256), 0, stream>>>(x, XS, B, E, K);

  if (canFused) {
    unsigned short* Wihp = (unsigned short*)alloc(szW);
    unsigned short* Whhp = (unsigned short*)alloc(szW);
    float* bihp          = (float*)alloc(szB3);
    float* bhhp          = (float*)alloc(szB3);
    unsigned short* hb1  = (unsigned short*)alloc(szHb1);
    unsigned short* GI   = (unsigned short*)alloc(szGI);
    unsigned short* Yb   = (unsigned short*)alloc(szY);
    unsigned int*   bar  = (unsigned int*)alloc(szBar);

    reorder_kernel<<<dim3(2048), dim3(256), 0, stream>>>(
        Wihb, Whhb, bih, bhh, Wihp, Whhp, bihp, bhhp, E);

    gemm256<<<dim3(N3 / 256, (int)(M_GI / 128)), dim3(512), 0, stream>>>(
        XS, Wihp, bihp, GI, (int)M_GI, N3, E);
    hipMemsetAsync(bar, 0, szBar, stream);

    const unsigned short* GIc = GI;
    const unsigned short* Whhc = Whhp;
    const float* bhhc = bhhp;
    const unsigned short* h0c = hb0;
    void* args[] = { (void*)&GIc, (void*)&Whhc, (void*)&bhhc, (void*)&h0c,
                     (void*)&hb0, (void*)&hb1, (void*)&Yb,
                     (void*)&bar, (void*)&B, (void*)&E, (void*)&K, (void*)&net };
    hipError_t ce = hipLaunchCooperativeKernel(
        (const void*)gru_rec8, dim3(net, nbt), dim3(512), args, 0, stream);
    if (ce != hipSuccess) {
      (void)hipGetLastError();
      gru_rec8<<<dim3(net, nbt), dim3(512), 0, stream>>>(
          GIc, Whhc, bhhc, h0c, hb0, hb1, Yb, bar, B, E, K, net);
    }
    transpose_y<<<dim3(E / 64, B), dim3(256), 0, stream>>>(Yb, out, B, E, K);
    return;
  }

  // -------- fallback: per-step GEMMs (round-1 path, normal layout) -----
  int haveY = rem >= szY;
  unsigned short* Yb = haveY ? (unsigned short*)alloc(szY) : nullptr;
  int pgrid = (int)((BE / 4 + 255) / 256);
  for (int k = 0; k < K; ++k) {
    gemm_bt<1><<<dim3(N3 / BN, B / BM), dim3(256), 0, stream>>>(
        XS + (size_t)k * B * E, Wihb, bih, nullptr, GIstep, B, N3, E);
    gemm_bt<0><<<dim3(N3 / BN, B / BM), dim3(256), 0, stream>>>(
        hb0, Whhb, bhh, gh, nullptr, B, N3, E);
    if (haveY)
      gru_pointwise<1><<<dim3(pgrid), dim3(256), 0, stream>>>(
          GIstep, gh, h32, hb0, Yb, out, k, B, E, K);
    else
      gru_pointwise<2><<<dim3(pgrid), dim3(256), 0, stream>>>(
          GIstep, gh, h32, hb0, nullptr, out, k, B, E, K);
  }
  if (haveY)
    transpose_y<<<dim3(E / 64, B), dim3(256), 0, stream>>>(Yb, out, B, E, K);
}

// Round 13
// 1900.078 us; speedup vs baseline: 1.8742x; 1.8742x over previous
//
#include <hip/hip_runtime.h>
#include <hip/hip_bf16.h>
#include <math.h>

typedef __bf16 bf16x8 __attribute__((ext_vector_type(8)));
typedef float f32x4 __attribute__((ext_vector_type(4)));
typedef unsigned short u16x8 __attribute__((ext_vector_type(8)));

#define VMW(N) asm volatile("s_waitcnt vmcnt(" #N ")" ::: "memory")
#define LGKM0  asm volatile("s_waitcnt lgkmcnt(0)" ::: "memory")
#define CFENCE asm volatile("" ::: "memory")

__device__ inline unsigned short f2b(float f) {
  union { float f; unsigned u; } v; v.f = f;
  unsigned u = v.u;
  return (unsigned short)((u + 0x7fffu + ((u >> 16) & 1u)) >> 16);
}
__device__ inline float b2f(unsigned short s) {
  union { unsigned u; float f; } v; v.u = ((unsigned)s) << 16;
  return v.f;
}
__device__ inline float sigm(float x) { return 1.f / (1.f + __expf(-x)); }
__device__ inline float tanh_f(float x) {
  float e = __expf(2.f * x);
  return 1.f - 2.f / (e + 1.f);
}
// cached global->LDS 16B
__device__ inline void gll16(const unsigned short* g, unsigned short* l) {
  __builtin_amdgcn_global_load_lds(
      (const __attribute__((address_space(1))) void*)g,
      (__attribute__((address_space(3))) void*)l, 16, 0, 0);
}
// coherent (sc0|sc1) global->LDS 16B (IF$-coherent, for the h exchange)
__device__ inline void gll16u(const unsigned short* g, unsigned short* l) {
  __builtin_amdgcn_global_load_lds(
      (const __attribute__((address_space(1))) void*)g,
      (__attribute__((address_space(3))) void*)l, 16, 0, 17);
}
__device__ inline void as64(unsigned short* p, unsigned long long v) {
  __hip_atomic_store((unsigned long long*)p, v, __ATOMIC_RELAXED,
                     __HIP_MEMORY_SCOPE_AGENT);
}
__device__ inline void waitflag(const unsigned int* p) {
  while (__hip_atomic_load(p, __ATOMIC_RELAXED, __HIP_MEMORY_SCOPE_AGENT) == 0)
    __builtin_amdgcn_s_sleep(1);
}

// -------------------- prep: weights->bf16, h init --------------------
__global__ __launch_bounds__(256) void prep_kernel(
    const float* __restrict__ Wih, const float* __restrict__ Whh,
    const float* __restrict__ c, unsigned short* __restrict__ Wihb,
    unsigned short* __restrict__ Whhb, unsigned short* __restrict__ hbf,
    float* __restrict__ h32, long nW, long nH)
{
  long stride = (long)gridDim.x * blockDim.x;
  long t0 = (long)blockIdx.x * blockDim.x + threadIdx.x;
  for (long i = t0; i < nW; i += stride) {
    Wihb[i] = f2b(Wih[i]);
    Whhb[i] = f2b(Whh[i]);
  }
  for (long i = t0; i < nH; i += stride) {
    float v = c[i];
    h32[i] = v;
    hbf[i] = f2b(v);
  }
}

// ---- reorder rows: row' = (g6*3+g)*64+elo  <-  row = g*E + g6*64 + elo ----
__global__ __launch_bounds__(256) void reorder_kernel(
    const unsigned short* __restrict__ Wihb, const unsigned short* __restrict__ Whhb,
    const float* __restrict__ bih, const float* __restrict__ bhh,
    unsigned short* __restrict__ Wihp, unsigned short* __restrict__ Whhp,
    float* __restrict__ bihp, float* __restrict__ bhhp, int E)
{
  int N3 = 3 * E;
  long total = (long)N3 * E;
  long stride = (long)gridDim.x * blockDim.x;
  long t0 = (long)blockIdx.x * blockDim.x + threadIdx.x;
  for (long i = t0; i < total; i += stride) {
    int rp = (int)(i / E);
    int col = (int)(i - (long)rp * E);
    int g6 = rp / 192, rem = rp - g6 * 192;
    int g = rem >> 6, elo = rem & 63;
    long src = ((long)g * E + g6 * 64 + elo) * E + col;
    Wihp[i] = Wihb[src];
    Whhp[i] = Whhb[src];
  }
  for (long i = t0; i < N3; i += stride) {
    int rp = (int)i;
    int g6 = rp / 192, rem = rp - g6 * 192;
    int g = rem >> 6, elo = rem & 63;
    bihp[i] = bih[(long)g * E + g6 * 64 + elo];
    bhhp[i] = bhh[(long)g * E + g6 * 64 + elo];
  }
}

// -------------------- transpose x (B,E,K) -> XS (K,B,E) bf16 ----------
__global__ __launch_bounds__(256) void transpose_x(
    const float* __restrict__ x, unsigned short* __restrict__ XS,
    int B, int E, int K)
{
  __shared__ float T[64][65];
  int e0 = blockIdx.x * 64;
  int b = blockIdx.y;
  int t = threadIdx.x;
  const float* xb = x + ((long)b * E + e0) * K;
#pragma unroll
  for (int i = 0; i < 4; ++i) {
    int cidx = i * 256 + t;
    int e = cidx >> 4;
    int f4 = cidx & 15;
    float4 v = *(const float4*)(xb + (long)e * K + f4 * 4);
    T[e][f4 * 4 + 0] = v.x;
    T[e][f4 * 4 + 1] = v.y;
    T[e][f4 * 4 + 2] = v.z;
    T[e][f4 * 4 + 3] = v.w;
  }
  __syncthreads();
#pragma unroll
  for (int i = 0; i < 16; ++i) {
    int cidx = i * 256 + t;
    int k = cidx >> 6;
    int e = cidx & 63;
    if (k < K - 1)
      XS[((long)(k + 1) * B + b) * E + e0 + e] = f2b(T[e][k]);
  }
}

// ---------- gemm256: C(M,N)=A(M,K)@Bw(N,K)^T + bias, bf16 out --------
__global__ __launch_bounds__(512, 1)
void gemm256(const unsigned short* __restrict__ A,
             const unsigned short* __restrict__ Bw,
             const float* __restrict__ bias,
             unsigned short* __restrict__ Cb,
             int M, int N, int K)
{
  __shared__ __align__(16) unsigned short sm[3 * 24576];  // 144 KB

  int nwg = gridDim.x * gridDim.y;
  int wg = blockIdx.y * gridDim.x + blockIdx.x;
  if ((nwg & 7) == 0) { int ch = nwg >> 3; wg = (wg & 7) * ch + (wg >> 3); }
  int tx = wg % gridDim.x;   // N tile (256)
  int ty = wg / gridDim.x;   // M tile (128)

  const int tid = threadIdx.x;
  const int lane = tid & 63;
  const int wave = tid >> 6;
  const int wm = wave >> 2;
  const int wn = wave & 3;
  const int q = lane >> 4;
  const int l15 = lane & 15;

  const long a_base = (long)ty * 128 * K;
  const long b_base = (long)tx * 256 * K;

  long a_src[2]; int a_dst[2];
#pragma unroll
  for (int i = 0; i < 2; ++i) {
    int c = i * 512 + tid;
    int row = c >> 3;
    int g8 = (c & 7) ^ (row & 7);
    a_src[i] = a_base + (long)row * K + g8 * 8;
    a_dst[i] = c * 8;
  }
  long b_src[4]; int b_dst[4];
#pragma unroll
  for (int i = 0; i < 4; ++i) {
    int c = i * 512 + tid;
    int row = c >> 3;
    int g8 = (c & 7) ^ (row & 7);
    b_src[i] = b_base + (long)row * K + g8 * 8;
    b_dst[i] = c * 8;
  }

  int a_ro[4], b_ro[4];
#pragma unroll
  for (int mi = 0; mi < 4; ++mi) {
    int lr = wm * 64 + mi * 16 + l15;
    a_ro[mi] = lr * 64;
  }
#pragma unroll
  for (int ni = 0; ni < 4; ++ni) {
    int col = wn * 64 + ni * 16 + l15;
    b_ro[ni] = col * 64;
  }

  f32x4 acc[4][4] = {};

  const int NT = K >> 6;
#pragma unroll
  for (int t = 0; t < 2; ++t) {
    unsigned short* As = sm + t * 24576;
    unsigned short* Bs = As + 8192;
#pragma unroll
    for (int i = 0; i < 2; ++i) gll16(A + a_src[i] + t * 64, As + a_dst[i]);
#pragma unroll
    for (int i = 0; i < 4; ++i) gll16(Bw + b_src[i] + t * 64, Bs + b_dst[i]);
  }

  for (int kt = 0; kt < NT; ++kt) {
    if (kt >= NT - 2) VMW(0); else VMW(6);
    __builtin_amdgcn_s_barrier();
    CFENCE;
    const unsigned short* As = sm + (kt % 3) * 24576;
    const unsigned short* Bs = As + 8192;
    unsigned short* As2 = sm + ((kt + 2) % 3) * 24576;
    unsigned short* Bs2 = As2 + 8192;
    const bool st = (kt + 2 < NT);
    const int ko = (kt + 2) * 64;

    if (st) {
      gll16(A + a_src[0] + ko, As2 + a_dst[0]);
      gll16(A + a_src[1] + ko, As2 + a_dst[1]);
      gll16(Bw + b_src[0] + ko, Bs2 + b_dst[0]);
    }
    {
      const int c8 = q;
      bf16x8 af[4], bf_[4];
#pragma unroll
      for (int mi = 0; mi < 4; ++mi) {
        int lr = wm * 64 + mi * 16 + l15;
        af[mi] = *(const bf16x8*)&As[a_ro[mi] + ((c8 ^ (lr & 7)) << 3)];
      }
#pragma unroll
      for (int ni = 0; ni < 4; ++ni) {
        int col = wn * 64 + ni * 16 + l15;
        bf_[ni] = *(const bf16x8*)&Bs[b_ro[ni] + ((c8 ^ (col & 7)) << 3)];
      }
      __builtin_amdgcn_s_setprio(1);
#pragma unroll
      for (int mi = 0; mi < 4; ++mi)
#pragma unroll
        for (int ni = 0; ni < 4; ++ni)
          acc[mi][ni] = __builtin_amdgcn_mfma_f32_16x16x32_bf16(
              af[mi], bf_[ni], acc[mi][ni], 0, 0, 0);
      __builtin_amdgcn_s_setprio(0);
    }
    LGKM0;
    __builtin_amdgcn_s_barrier();
    CFENCE;
    if (st) {
      gll16(Bw + b_src[1] + ko, Bs2 + b_dst[1]);
      gll16(Bw + b_src[2] + ko, Bs2 + b_dst[2]);
      gll16(Bw + b_src[3] + ko, Bs2 + b_dst[3]);
    }
    {
      const int c8 = 4 + q;
      bf16x8 af[4], bf_[4];
#pragma unroll
      for (int mi = 0; mi < 4; ++mi) {
        int lr = wm * 64 + mi * 16 + l15;
        af[mi] = *(const bf16x8*)&As[a_ro[mi] + ((c8 ^ (lr & 7)) << 3)];
      }
#pragma unroll
      for (int ni = 0; ni < 4; ++ni) {
        int col = wn * 64 + ni * 16 + l15;
        bf_[ni] = *(const bf16x8*)&Bs[b_ro[ni] + ((c8 ^ (col & 7)) << 3)];
      }
      __builtin_amdgcn_s_setprio(1);
#pragma unroll
      for (int mi = 0; mi < 4; ++mi)
#pragma unroll
        for (int ni = 0; ni < 4; ++ni)
          acc[mi][ni] = __builtin_amdgcn_mfma_f32_16x16x32_bf16(
              af[mi], bf_[ni], acc[mi][ni], 0, 0, 0);
      __builtin_amdgcn_s_setprio(0);
    }
    LGKM0;
  }

  long crow0 = (long)ty * 128 + wm * 64;
  long ccol0 = (long)tx * 256 + wn * 64;
#pragma unroll
  for (int mi = 0; mi < 4; ++mi) {
#pragma unroll
    for (int ni = 0; ni < 4; ++ni) {
      long col = ccol0 + ni * 16 + l15;
      float bv = bias[col];
#pragma unroll
      for (int j = 0; j < 4; ++j) {
        long row = crow0 + mi * 16 + (q << 2) + j;
        Cb[row * N + col] = f2b(acc[mi][ni][j] + bv);
      }
    }
  }
}

// -------------------- GEMM (fallback path): 128x128 m97-style ---------
#define BM 128
#define BN 128
#define BKS 64

template<int OUTBF>
__global__ __launch_bounds__(256)
void gemm_bt(const unsigned short* __restrict__ A,
             const unsigned short* __restrict__ Bw,
             const float* __restrict__ bias,
             float* __restrict__ Cf, unsigned short* __restrict__ Cb,
             int M, int N, int K)
{
  __shared__ __align__(16) unsigned short As[BM * BKS];
  __shared__ __align__(16) unsigned short Bs[BN * BKS];

  int nwg = gridDim.x * gridDim.y;
  int wg = blockIdx.y * gridDim.x + blockIdx.x;
  if ((nwg & 7) == 0) { int ch = nwg >> 3; wg = (wg & 7) * ch + (wg >> 3); }
  int tx = wg % gridDim.x;
  int ty = wg / gridDim.x;

  const int tid = threadIdx.x;
  const int lane = tid & 63;
  const int wave = tid >> 6;
  const int wr = wave >> 1, wc = wave & 1;

  f32x4 acc[4][4] = {};

  const long a_base = (long)ty * BM * K;
  const long b_base = (long)tx * BN * K;

  for (int kt = 0; kt < K; kt += BKS) {
    __syncthreads();
#pragma unroll
    for (int i = 0; i < 4; ++i) {
      int c = i * 256 + tid;
      int row = c >> 3, sc = c & 7;
      int gcol8 = sc ^ (row & 7);
      const unsigned short* ga = A + a_base + (long)row * K + kt + gcol8 * 8;
      const unsigned short* gb = Bw + b_base + (long)row * K + kt + gcol8 * 8;
      int cbase = (i * 256 + wave * 64) * 8;
      gll16(ga, &As[cbase]);
      gll16(gb, &Bs[cbase]);
    }
    __syncthreads();
#pragma unroll
    for (int kk = 0; kk < BKS; kk += 32) {
      int kidx = kk + ((lane >> 4) << 3);
      int c8 = kidx >> 3;
      bf16x8 af[4], bfv[4];
#pragma unroll
      for (int m = 0; m < 4; ++m) {
        int row = wr * 64 + m * 16 + (lane & 15);
        af[m] = *(const bf16x8*)&As[row * BKS + ((c8 ^ (row & 7)) << 3)];
      }
#pragma unroll
      for (int n = 0; n < 4; ++n) {
        int col = wc * 64 + n * 16 + (lane & 15);
        bfv[n] = *(const bf16x8*)&Bs[col * BKS + ((c8 ^ (col & 7)) << 3)];
      }
#pragma unroll
      for (int m = 0; m < 4; ++m)
#pragma unroll
        for (int n = 0; n < 4; ++n)
          acc[m][n] = __builtin_amdgcn_mfma_f32_16x16x32_bf16(
              af[m], bfv[n], acc[m][n], 0, 0, 0);
    }
  }

  long crow0 = (long)ty * BM + wr * 64;
  long ccol0 = (long)tx * BN + wc * 64;
#pragma unroll
  for (int m = 0; m < 4; ++m) {
#pragma unroll
    for (int n = 0; n < 4; ++n) {
      long col = ccol0 + n * 16 + (lane & 15);
      float bv = bias[col];
#pragma unroll
      for (int j = 0; j < 4; ++j) {
        long row = crow0 + m * 16 + ((lane >> 4) << 2) + j;
        float v = acc[m][n][j] + bv;
        if (OUTBF) Cb[row * N + col] = f2b(v);
        else       Cf[row * N + col] = v;
      }
    }
  }
}

// -------------------- persistent fused recurrence v9 ------------------
// R10's verified kernel with the GLOBAL STEP BARRIER replaced by per-chunk
// dataflow flags: producer (bt,e6) publishes flag[k+1][bt][e6] after its
// stores drain; consumers poll a chunk's flag just before issuing that
// tile's DMA (rotation => own chunk first from Ys, zero wait). WGs
// self-pace; skew is absorbed, not amplified. h ping-pong -> 4-deep ring
// (flags bound skew < 2 steps; 4 gives margin).
__global__ __launch_bounds__(512, 1)
void gru_rec9(const unsigned short* __restrict__ GI,
              const unsigned short* __restrict__ Whp,
              const float* __restrict__ bhp,
              unsigned short* __restrict__ hbase,   // 4 buffers of B*E
              long BEsz,
              unsigned short* __restrict__ Y,
              unsigned int* __restrict__ flag,      // (K+1) x 16 x 16
              int B, int E, int K)
{
  __shared__ __align__(16) unsigned char smem[156672];     // 153 KB
  unsigned short* Ah  = (unsigned short*)smem;             // 6 x 8KB A ring
  unsigned short* Bss = (unsigned short*)(smem + 49152);   // 3 x 24KB B ring
  unsigned short* GIs = (unsigned short*)(smem + 122880);  // 24KB
  unsigned short* Ys  = (unsigned short*)(smem + 147456);  // 9KB persistent h
  float* Red = (float*)smem;  // gate-phase alias over dead A/B-head space

  const int N3 = 3 * E;
  const int e6 = blockIdx.x;           // 0..15; e6%8 -> XCD panel pinning
  const int bt = blockIdx.y;           // 0..15
  const int b0 = bt << 6;
  const int ec0 = e6 * 192;
  const int ecol0 = e6 << 6;
  const int rot = e6 & 15;             // rotation start = own chunk
  const int tid = threadIdx.x;
  const int lane = tid & 63;
  const int w = tid >> 6;
  const int ew = w >> 1;
  const int kw = w & 1;
  const int q = lane >> 4;
  const int l15 = lane & 15;
  const int el = (ew << 4) + l15;
  const int c8 = (kw << 2) + q;
  const int axo = (c8 ^ (l15 & 7)) << 3;
  const int bxo = (c8 ^ (el & 7)) << 3;

  const int arow = tid >> 3;
  const int ag8 = (tid & 7) ^ (arow & 7);
  const long a_goff = (long)(b0 + arow) * E + ag8 * 8;
  const int a_dst = tid * 8;
  long b_goff[3]; int b_dst[3];
#pragma unroll
  for (int i = 0; i < 3; ++i) {
    int c = i * 512 + tid;
    int row = c >> 3;
    int g8 = (c & 7) ^ (row & 7);
    b_goff[i] = (long)(ec0 + row) * E + g8 * 8;
    b_dst[i] = c * 8;
  }
  long gi_off[3]; int gi_dst[3];
#pragma unroll
  for (int i = 0; i < 3; ++i) {
    int c = i * 512 + tid;
    int row = c / 24, cc = c - row * 24;
    gi_off[i] = (long)(b0 + row) * N3 + ec0 + cc * 8;
    gi_dst[i] = c * 8;
  }

  const float bh0 = bhp[ec0 + el];
  const float bh1 = bhp[ec0 + 64 + el];
  const float bh2 = bhp[ec0 + 128 + el];

  // Ys preload: persistent per-WG h cache (h_0 lives in hbase slot 0)
  if (kw == 0) {
#pragma unroll
    for (int m = 0; m < 4; ++m)
#pragma unroll
      for (int j = 0; j < 4; ++j) {
        int row = m * 16 + q * 4 + j;
        Ys[row * 72 + el] = hbase[(long)(b0 + row) * E + ecol0 + el];
      }
  }
  __syncthreads();

  // ---- pre-loop: B tiles rot, rot+1 -> slots 0,1 (h-independent) ----
#pragma unroll
  for (int i = 0; i < 3; ++i)
    gll16(Whp + b_goff[i] + rot * 64, Bss + b_dst[i]);
#pragma unroll
  for (int i = 0; i < 3; ++i)
    gll16(Whp + b_goff[i] + ((rot + 1) & 15) * 64, Bss + 12288 + b_dst[i]);

  for (int k = 0; k < K; ++k) {
    const unsigned short* hprev = hbase + (size_t)(k & 3) * BEsz;
    unsigned short* hnext = hbase + (size_t)((k + 1) & 3) * BEsz;
    const unsigned short* GIk = GI + (long)k * B * N3;
    const unsigned int* fstep = flag + ((long)k * 16 + bt) * 16;

    // ---- prolog: own tile from Ys (LDS->LDS); A tiles rot+1..4; GI ----
    {
      int row = tid >> 3;
      int g8 = (tid & 7) ^ (row & 7);
      u16x8 v = *(const u16x8*)&Ys[row * 72 + g8 * 8];
      *(u16x8*)&Ah[a_dst] = v;     // slot 0 = tile rot (own h chunk)
    }
#pragma unroll
    for (int t = 1; t < 5; ++t) {
      int c = (rot + t) & 15;
      if (k > 0) waitflag(fstep + c);
      gll16u(hprev + a_goff + c * 64, Ah + t * 4096 + a_dst);
    }
#pragma unroll
    for (int i = 0; i < 3; ++i) gll16(GIk + gi_off[i], GIs + gi_dst[i]);

    f32x4 acc[4][3];
#pragma unroll
    for (int m = 0; m < 4; ++m)
#pragma unroll
      for (int g = 0; g < 3; ++g)
        acc[m][g] = (f32x4){0.f, 0.f, 0.f, 0.f};

#pragma unroll
    for (int kt = 0; kt < 16; ++kt) {
      // wait table (R10-verified): [10,10,5,...,5,4,3,3,0]
      if (kt <= 1)       VMW(10);
      else if (kt <= 11) VMW(5);
      else if (kt == 12) VMW(4);
      else if (kt == 15) VMW(0);
      else               VMW(3);
      LGKM0;
      __builtin_amdgcn_s_barrier();
      CFENCE;

      if (kt + 2 < 16) {
#pragma unroll
        for (int i = 0; i < 3; ++i)
          gll16(Whp + b_goff[i] + ((rot + kt + 2) & 15) * 64,
                Bss + ((kt + 2) % 3) * 12288 + b_dst[i]);
      }
      if (kt + 5 < 16) {
        int c = (rot + kt + 5) & 15;
        if (k > 0) waitflag(fstep + c);
        gll16u(hprev + a_goff + c * 64, Ah + ((kt + 5) % 6) * 4096 + a_dst);
      }

      const unsigned short* Ab = Ah + (kt % 6) * 4096;
      const unsigned short* Bb = Bss + (kt % 3) * 12288;
      bf16x8 af[4], bfg[3];
#pragma unroll
      for (int m = 0; m < 4; ++m)
        af[m] = *(const bf16x8*)&Ab[(m * 16 + l15) * 64 + axo];
#pragma unroll
      for (int g = 0; g < 3; ++g)
        bfg[g] = *(const bf16x8*)&Bb[(g * 64 + el) * 64 + bxo];

      __builtin_amdgcn_s_setprio(1);
#pragma unroll
      for (int g = 0; g < 3; ++g)
#pragma unroll
        for (int m = 0; m < 4; ++m)
          acc[m][g] = __builtin_amdgcn_mfma_f32_16x16x32_bf16(
              af[m], bfg[g], acc[m][g], 0, 0, 0);
      __builtin_amdgcn_s_setprio(0);
    }

    // ---- K-split reduce (Red aliases dead A/B LDS) + fused gates ----
    __syncthreads();
    float* rp = &Red[((ew << 6) + lane) * 49];
    if (kw == 1) {
#pragma unroll
      for (int m = 0; m < 4; ++m)
#pragma unroll
        for (int g = 0; g < 3; ++g)
#pragma unroll
          for (int cc = 0; cc < 4; ++cc)
            rp[(m * 3 + g) * 4 + cc] = acc[m][g][cc];
    }
    __syncthreads();
    if (kw == 0) {
#pragma unroll
      for (int m = 0; m < 4; ++m) {
#pragma unroll
        for (int j = 0; j < 4; ++j) {
          int row = m * 16 + q * 4 + j;
          float ghr = acc[m][0][j] + rp[(m * 3 + 0) * 4 + j];
          float ghz = acc[m][1][j] + rp[(m * 3 + 1) * 4 + j];
          float ghn = acc[m][2][j] + rp[(m * 3 + 2) * 4 + j];
          float gr = b2f(GIs[row * 192 + el]);
          float gz = b2f(GIs[row * 192 + 64 + el]);
          float gn = b2f(GIs[row * 192 + 128 + el]);
          float hu = b2f(Ys[row * 72 + el]);
          float r = sigm(gr + ghr + bh0);
          float z = sigm(gz + ghz + bh1);
          float n = tanh_f(gn + r * (ghn + bh2));
          float hv = (1.f - z) * n + z * hu;
          Ys[row * 72 + el] = f2b(hv);
        }
      }
    }
    __syncthreads();
    // ---- write-out: h_next coherent atomics, Y plain stores ----
    {
      int row = tid >> 3, cc = tid & 7;
      u16x8 v = *(const u16x8*)&Ys[row * 72 + cc * 8];
      unsigned* pv = (unsigned*)&v;
      unsigned long long s0 = ((unsigned long long)pv[1] << 32) | pv[0];
      unsigned long long s1 = ((unsigned long long)pv[3] << 32) | pv[2];
      unsigned short* hp = hnext + (long)(b0 + row) * E + ecol0 + cc * 8;
      as64(hp, s0);
      as64(hp + 4, s1);
      *(u16x8*)(Y + ((long)k * B + b0 + row) * E + ecol0 + cc * 8) = v;
    }
    // ---- publish own chunk for step k+1; NO global barrier ----
    if (k + 1 < K) {
      // B(k+1) prefetch (tiles rot, rot+1) stays in flight past the drain
#pragma unroll
      for (int i = 0; i < 3; ++i)
        gll16(Whp + b_goff[i] + rot * 64, Bss + b_dst[i]);
#pragma unroll
      for (int i = 0; i < 3; ++i)
        gll16(Whp + b_goff[i] + ((rot + 1) & 15) * 64, Bss + 12288 + b_dst[i]);
      VMW(6);                         // drains this wave's 3 stores
      __builtin_amdgcn_s_barrier();   // all waves' stores drained
      CFENCE;
      if (tid == 0)
        __hip_atomic_store(flag + ((long)(k + 1) * 16 + bt) * 16 + e6, 1u,
                           __ATOMIC_RELAXED, __HIP_MEMORY_SCOPE_AGENT);
    }
  }
}

// -------------------- pointwise GRU gates (fallback path) -------------
template<int YMODE>
__global__ __launch_bounds__(256)
void gru_pointwise(const unsigned short* __restrict__ GIk,
                   const float* __restrict__ gh,
                   float* __restrict__ h, unsigned short* __restrict__ hbf,
                   unsigned short* __restrict__ Yb,
                   float* __restrict__ out, int k, int B, int E, int K)
{
  long i4 = ((long)blockIdx.x * blockDim.x + threadIdx.x) * 4;
  if (i4 >= (long)B * E) return;
  long b = i4 / E;
  long e = i4 - b * E;
  long g0 = b * 3 * E + e;
  ushort4 ir = *(const ushort4*)(GIk + g0);
  ushort4 iz = *(const ushort4*)(GIk + g0 + E);
  ushort4 in4 = *(const ushort4*)(GIk + g0 + 2 * E);
  float4 hr = *(const float4*)(gh + g0);
  float4 hz = *(const float4*)(gh + g0 + E);
  float4 hn = *(const float4*)(gh + g0 + 2 * E);
  float4 hv = *(const float4*)(h + i4);

  float irf[4] = { b2f(ir.x), b2f(ir.y), b2f(ir.z), b2f(ir.w) };
  float izf[4] = { b2f(iz.x), b2f(iz.y), b2f(iz.z), b2f(iz.w) };
  float inf_[4] = { b2f(in4.x), b2f(in4.y), b2f(in4.z), b2f(in4.w) };
  float hrf[4] = { hr.x, hr.y, hr.z, hr.w };
  float hzf[4] = { hz.x, hz.y, hz.z, hz.w };
  float hnf[4] = { hn.x, hn.y, hn.z, hn.w };
  float hvf[4] = { hv.x, hv.y, hv.z, hv.w };
  float hnew[4];
#pragma unroll
  for (int j = 0; j < 4; ++j) {
    float r = sigm(irf[j] + hrf[j]);
    float z = sigm(izf[j] + hzf[j]);
    float n = tanh_f(inf_[j] + r * hnf[j]);
    hnew[j] = (1.f - z) * n + z * hvf[j];
  }
  *(float4*)(h + i4) = make_float4(hnew[0], hnew[1], hnew[2], hnew[3]);
  ushort4 hb = make_ushort4(f2b(hnew[0]), f2b(hnew[1]), f2b(hnew[2]), f2b(hnew[3]));
  *(ushort4*)(hbf + i4) = hb;
  if (YMODE == 1) {
    *(ushort4*)(Yb + ((long)k * B + b) * E + e) = hb;
  } else {
    float* o = out + (b * E + e) * K + k;
    o[0] = hnew[0]; o[K] = hnew[1]; o[2 * K] = hnew[2]; o[3 * K] = hnew[3];
  }
}

// -------------------- transpose Y (K,B,E) bf16 -> out (B,E,K) fp32 ----
__global__ __launch_bounds__(256)
void transpose_y(const unsigned short* __restrict__ Yv, float* __restrict__ out,
                 int B, int E, int K)
{
  __shared__ float T[64][65];
  int e0 = blockIdx.x * 64;
  int b = blockIdx.y;
  int t = threadIdx.x;
#pragma unroll
  for (int i = 0; i < 4; ++i) {
    int c = i * 256 + t;
    int k = c >> 4, f4 = c & 15;
    long off = ((long)k * B + b) * E + e0 + f4 * 4;
    ushort4 v = *(const ushort4*)(Yv + off);
    T[k][f4 * 4 + 0] = b2f(v.x); T[k][f4 * 4 + 1] = b2f(v.y);
    T[k][f4 * 4 + 2] = b2f(v.z); T[k][f4 * 4 + 3] = b2f(v.w);
  }
  __syncthreads();
#pragma unroll
  for (int i = 0; i < 4; ++i) {
    int c = i * 256 + t;
    int e = c >> 4, f4k = c & 15;
    float4 w;
    w.x = T[f4k * 4 + 0][e];
    w.y = T[f4k * 4 + 1][e];
    w.z = T[f4k * 4 + 2][e];
    w.w = T[f4k * 4 + 3][e];
    *(float4*)(out + ((long)b * E + e0 + e) * K + f4k * 4) = w;
  }
}

// -------------------- host launch -------------------------------------
extern "C" void kernel_launch(void* const* d_in, const int* in_sizes, int n_in,
                              void* d_out, int out_size, void* d_ws, size_t ws_size,
                              hipStream_t stream)
{
  const float* c   = (const float*)d_in[0];
  const float* x   = (const float*)d_in[1];
  const float* Wih = (const float*)d_in[2];
  const float* Whh = (const float*)d_in[3];
  const float* bih = (const float*)d_in[4];
  const float* bhh = (const float*)d_in[5];
  float* out = (float*)d_out;

  long BE = in_sizes[0];
  int E = (int)(sqrtf((float)(in_sizes[2] / 3)) + 0.5f);
  int B = (int)(BE / E);
  int K = (int)(in_sizes[1] / BE);
  int N3 = 3 * E;
  long M_GI = (long)K * B;

  char* w = (char*)d_ws;
  size_t used = 0;
  auto alloc = [&](size_t bytes) -> char* {
    char* p = w + used;
    used += (bytes + 255) & ~(size_t)255;
    return p;
  };
  size_t szHb1 = (((size_t)B * E * 2) + 255) & ~(size_t)255;
  unsigned short* Wihb  = (unsigned short*)alloc((size_t)N3 * E * 2);
  unsigned short* Whhb  = (unsigned short*)alloc((size_t)N3 * E * 2);
  unsigned short* hbM   = (unsigned short*)alloc(4 * szHb1);  // 4-deep h ring
  float* h32            = (float*)alloc((size_t)B * E * 4);
  float* gh             = (float*)alloc((size_t)B * N3 * 4);
  unsigned short* GIstep= (unsigned short*)alloc((size_t)B * N3 * 2);
  unsigned short* XS    = (unsigned short*)alloc((size_t)K * B * E * 2);

  size_t rem = (ws_size > used) ? ws_size - used : 0;
  size_t szW   = (((size_t)N3 * E * 2) + 255) & ~(size_t)255;
  size_t szB3  = (((size_t)N3 * 4) + 255) & ~(size_t)255;
  size_t szGI  = (((size_t)K * B * N3 * 2) + 255) & ~(size_t)255;
  size_t szY   = (((size_t)K * B * E * 2) + 255) & ~(size_t)255;
  size_t szFlag = (((size_t)(K + 1) * 16 * 16 * 4) + 255) & ~(size_t)255;

  bool canFused = (B == 1024) && (E == 1024) && (K == 64) &&
                  (rem >= 2 * szW + 2 * szB3 + szGI + szY + szFlag);

  long nW = (long)N3 * E;
  prep_kernel<<<dim3(2048), dim3(256), 0, stream>>>(Wih, Whh, c, Wihb, Whhb,
                                                    hbM, h32, nW, BE);
  hipMemsetAsync(XS, 0, (size_t)B * E * 2, stream);
  transpose_x<<<dim3(E / 64, B), dim3(256), 0, stream>>>(x, XS, B, E, K);

  if (canFused) {
    unsigned short* Wihp = (unsigned short*)alloc(szW);
    unsigned short* Whhp = (unsigned short*)alloc(szW);
    float* bihp          = (float*)alloc(szB3);
    float* bhhp          = (float*)alloc(szB3);
    unsigned short* GI   = (unsigned short*)alloc(szGI);
    unsigned short* Yb   = (unsigned short*)alloc(szY);
    unsigned int*   flag = (unsigned int*)alloc(szFlag);

    reorder_kernel<<<dim3(2048), dim3(256), 0, stream>>>(
        Wihb, Whhb, bih, bhh, Wihp, Whhp, bihp, bhhp, E);

    gemm256<<<dim3(N3 / 256, (int)(M_GI / 128)), dim3(512), 0, stream>>>(
        XS, Wihp, bihp, GI, (int)M_GI, N3, E);
    hipMemsetAsync(flag, 0, szFlag, stream);

    const unsigned short* GIc = GI;
    const unsigned short* Whhc = Whhp;
    const float* bhhc = bhhp;
    long BEsz = (long)szHb1 / 2;   // elements per h buffer (incl. pad)
    void* args[] = { (void*)&GIc, (void*)&Whhc, (void*)&bhhc,
                     (void*)&hbM, (void*)&BEsz, (void*)&Yb, (void*)&flag,
                     (void*)&B, (void*)&E, (void*)&K };
    hipError_t ce = hipLaunchCooperativeKernel(
        (const void*)gru_rec9, dim3(16, 16), dim3(512), args, 0, stream);
    if (ce != hipSuccess) {
      (void)hipGetLastError();
      gru_rec9<<<dim3(16, 16), dim3(512), 0, stream>>>(
          GIc, Whhc, bhhc, hbM, BEsz, Yb, flag, B, E, K);
    }
    transpose_y<<<dim3(E / 64, B), dim3(256), 0, stream>>>(Yb, out, B, E, K);
    return;
  }

  // -------- fallback: per-step GEMMs (round-1 path, normal layout) -----
  int haveY = rem >= szY;
  unsigned short* Yb = haveY ? (unsigned short*)alloc(szY) : nullptr;
  int pgrid = (int)((BE / 4 + 255) / 256);
  for (int k = 0; k < K; ++k) {
    gemm_bt<1><<<dim3(N3 / BN, B / BM), dim3(256), 0, stream>>>(
        XS + (size_t)k * B * E, Wihb, bih, nullptr, GIstep, B, N3, E);
    gemm_bt<0><<<dim3(N3 / BN, B / BM), dim3(256), 0, stream>>>(
        hbM, Whhb, bhh, gh, nullptr, B, N3, E);
    if (haveY)
      gru_pointwise<1><<<dim3(pgrid), dim3(256), 0, stream>>>(
          GIstep, gh, h32, hbM, Yb, out, k, B, E, K);
    else
      gru_pointwise<2><<<dim3(pgrid), dim3(256), 0, stream>>>(
          GIstep, gh, h32, hbM, nullptr, out, k, B, E, K);
  }
  if (haveY)
    transpose_y<<<dim3(E / 64, B), dim3(256), 0, stream>>>(Yb, out, B, E, K);
}

// Round 14
// 1446.390 us; speedup vs baseline: 2.4621x; 1.3137x over previous
//
#include <hip/hip_runtime.h>
#include <hip/hip_bf16.h>
#include <math.h>

typedef __bf16 bf16x8 __attribute__((ext_vector_type(8)));
typedef float f32x4 __attribute__((ext_vector_type(4)));
typedef unsigned short u16x8 __attribute__((ext_vector_type(8)));

#define VMW(N) asm volatile("s_waitcnt vmcnt(" #N ")" ::: "memory")
#define LGKM0  asm volatile("s_waitcnt lgkmcnt(0)" ::: "memory")
#define CFENCE asm volatile("" ::: "memory")

__device__ inline unsigned short f2b(float f) {
  union { float f; unsigned u; } v; v.f = f;
  unsigned u = v.u;
  return (unsigned short)((u + 0x7fffu + ((u >> 16) & 1u)) >> 16);
}
__device__ inline float b2f(unsigned short s) {
  union { unsigned u; float f; } v; v.u = ((unsigned)s) << 16;
  return v.f;
}
__device__ inline float sigm(float x) { return 1.f / (1.f + __expf(-x)); }
__device__ inline float tanh_f(float x) {
  float e = __expf(2.f * x);
  return 1.f - 2.f / (e + 1.f);
}
// cached global->LDS 16B
__device__ inline void gll16(const unsigned short* g, unsigned short* l) {
  __builtin_amdgcn_global_load_lds(
      (const __attribute__((address_space(1))) void*)g,
      (__attribute__((address_space(3))) void*)l, 16, 0, 0);
}
// coherent (sc0|sc1) global->LDS 16B (IF$-coherent, for the h exchange)
__device__ inline void gll16u(const unsigned short* g, unsigned short* l) {
  __builtin_amdgcn_global_load_lds(
      (const __attribute__((address_space(1))) void*)g,
      (__attribute__((address_space(3))) void*)l, 16, 0, 17);
}
__device__ inline void as64(unsigned short* p, unsigned long long v) {
  __hip_atomic_store((unsigned long long*)p, v, __ATOMIC_RELAXED,
                     __HIP_MEMORY_SCOPE_AGENT);
}

// -------------------- prep (fallback path) ----------------------------
__global__ __launch_bounds__(256) void prep_kernel(
    const float* __restrict__ Wih, const float* __restrict__ Whh,
    const float* __restrict__ c, unsigned short* __restrict__ Wihb,
    unsigned short* __restrict__ Whhb, unsigned short* __restrict__ hbf,
    float* __restrict__ h32, long nW, long nH)
{
  long stride = (long)gridDim.x * blockDim.x;
  long t0 = (long)blockIdx.x * blockDim.x + threadIdx.x;
  for (long i = t0; i < nW; i += stride) {
    Wihb[i] = f2b(Wih[i]);
    Whhb[i] = f2b(Whh[i]);
  }
  for (long i = t0; i < nH; i += stride) {
    float v = c[i];
    h32[i] = v;
    hbf[i] = f2b(v);
  }
}

// ---- fused prep+reorder (canFused): fp32 -> reordered bf16 directly --
// row' = (g6*3+g)*64+elo <- row = g*E + g6*64 + elo
__global__ __launch_bounds__(256) void prep2_kernel(
    const float* __restrict__ Wih, const float* __restrict__ Whh,
    const float* __restrict__ c, const float* __restrict__ bih,
    const float* __restrict__ bhh,
    unsigned short* __restrict__ Wihp, unsigned short* __restrict__ Whhp,
    float* __restrict__ bihp, float* __restrict__ bhhp,
    unsigned short* __restrict__ hb0, int E, long nH)
{
  int N3 = 3 * E;
  long total = (long)N3 * E;
  long stride = (long)gridDim.x * blockDim.x;
  long t0 = (long)blockIdx.x * blockDim.x + threadIdx.x;
  for (long i = t0; i < total; i += stride) {
    int rp = (int)(i / E);
    int col = (int)(i - (long)rp * E);
    int g6 = rp / 192, rem = rp - g6 * 192;
    int g = rem >> 6, elo = rem & 63;
    long src = ((long)g * E + g6 * 64 + elo) * E + col;
    Wihp[i] = f2b(Wih[src]);
    Whhp[i] = f2b(Whh[src]);
  }
  for (long i = t0; i < N3; i += stride) {
    int rp = (int)i;
    int g6 = rp / 192, rem = rp - g6 * 192;
    int g = rem >> 6, elo = rem & 63;
    bihp[i] = bih[(long)g * E + g6 * 64 + elo];
    bhhp[i] = bhh[(long)g * E + g6 * 64 + elo];
  }
  for (long i = t0; i < nH; i += stride)
    hb0[i] = f2b(c[i]);
}

// ---- reorder (fallback variant kept for non-fused paths; unused) -----

// -------------------- transpose x (B,E,K) -> XS (K,B,E) bf16 ----------
__global__ __launch_bounds__(256) void transpose_x(
    const float* __restrict__ x, unsigned short* __restrict__ XS,
    int B, int E, int K)
{
  __shared__ float T[64][65];
  int e0 = blockIdx.x * 64;
  int b = blockIdx.y;
  int t = threadIdx.x;
  const float* xb = x + ((long)b * E + e0) * K;
#pragma unroll
  for (int i = 0; i < 4; ++i) {
    int cidx = i * 256 + t;
    int e = cidx >> 4;
    int f4 = cidx & 15;
    float4 v = *(const float4*)(xb + (long)e * K + f4 * 4);
    T[e][f4 * 4 + 0] = v.x;
    T[e][f4 * 4 + 1] = v.y;
    T[e][f4 * 4 + 2] = v.z;
    T[e][f4 * 4 + 3] = v.w;
  }
  __syncthreads();
#pragma unroll
  for (int i = 0; i < 16; ++i) {
    int cidx = i * 256 + t;
    int k = cidx >> 6;
    int e = cidx & 63;
    if (k < K - 1)
      XS[((long)(k + 1) * B + b) * E + e0 + e] = f2b(T[e][k]);
  }
}

// ---------- gemm256k32: 256x256 tile, BK=32, ring-3, 2 phases/K-tile --
// 512 thr = 8 waves (2M x 4N), per-wave 128x64 out (acc[8][4]).
// Each phase: stage one operand of tile t+2 (2 gll16) || 4-8 ds_read_b128
// || 16 MFMA under setprio; raw barrier per phase; counted VMW(4) once
// per K-tile (VMW(0) only at the last). LDS 96 KB.
__global__ __launch_bounds__(512, 1)
void gemm256k32(const unsigned short* __restrict__ A,
                const unsigned short* __restrict__ Bw,
                const float* __restrict__ bias,
                unsigned short* __restrict__ Cb,
                int M, int N, int K)
{
  __shared__ __align__(16) unsigned short sm[3][16384];  // [slot][A8192|B8192]

  int nwg = gridDim.x * gridDim.y;
  int wg = blockIdx.y * gridDim.x + blockIdx.x;
  if ((nwg & 7) == 0) { int ch = nwg >> 3; wg = (wg & 7) * ch + (wg >> 3); }
  int tx = wg % gridDim.x;   // N tile (256)
  int ty = wg / gridDim.x;   // M tile (256)

  const int tid = threadIdx.x;
  const int lane = tid & 63;
  const int wave = tid >> 6;
  const int wm = wave >> 2;        // 0..1
  const int wn = wave & 3;         // 0..3
  const int q = lane >> 4;
  const int l15 = lane & 15;

  const long a_base = (long)ty * 256 * K;
  const long b_base = (long)tx * 256 * K;

  // staging: 2 chunks (16B) per thread per operand-tile; source pre-swizzled
  long ab_off[2]; int dstc[2];
#pragma unroll
  for (int i = 0; i < 2; ++i) {
    int c = i * 512 + tid;           // 0..1023 chunks (row = c>>2, grp = c&3)
    int row = c >> 2;
    int g4 = (c & 3) ^ (row & 3);
    ab_off[i] = (long)row * K + g4 * 8;
    dstc[i] = c * 8;                 // halfword offset (linear in tid)
  }

  int arow[8], bcol[4];
#pragma unroll
  for (int mi = 0; mi < 8; ++mi) arow[mi] = wm * 128 + mi * 16 + l15;
#pragma unroll
  for (int ni = 0; ni < 4; ++ni) bcol[ni] = wn * 64 + ni * 16 + l15;

  f32x4 acc[8][4] = {};

  const int NT = K >> 5;           // 32
  // prologue: tiles 0,1 -> slots 0,1
#pragma unroll
  for (int t = 0; t < 2; ++t) {
#pragma unroll
    for (int i = 0; i < 2; ++i)
      gll16(A + a_base + ab_off[i] + t * 32, &sm[t][dstc[i]]);
#pragma unroll
    for (int i = 0; i < 2; ++i)
      gll16(Bw + b_base + ab_off[i] + t * 32, &sm[t][8192 + dstc[i]]);
  }

  for (int t = 0; t < NT; ++t) {
    const int rs = t % 3;
    const int ws = (t + 2) % 3;
    const bool st = (t + 2 < NT);
    const unsigned short* As = sm[rs];
    const unsigned short* Bs = sm[rs] + 8192;

    // ---- phase 0 (mh=0): stage A(t+2); read af[0..3]+bf[0..3]; 16 MFMA
    if (t == NT - 1) VMW(0); else VMW(4);
    __builtin_amdgcn_s_barrier();
    CFENCE;
    if (st) {
#pragma unroll
      for (int i = 0; i < 2; ++i)
        gll16(A + a_base + ab_off[i] + (t + 2) * 32, &sm[ws][dstc[i]]);
    }
    bf16x8 bf[4];
#pragma unroll
    for (int ni = 0; ni < 4; ++ni) {
      int r = bcol[ni];
      bf[ni] = *(const bf16x8*)&Bs[r * 32 + ((q ^ (r & 3)) << 3)];
    }
    {
      bf16x8 af[4];
#pragma unroll
      for (int mi = 0; mi < 4; ++mi) {
        int r = arow[mi];
        af[mi] = *(const bf16x8*)&As[r * 32 + ((q ^ (r & 3)) << 3)];
      }
      __builtin_amdgcn_s_setprio(1);
#pragma unroll
      for (int mi = 0; mi < 4; ++mi)
#pragma unroll
        for (int ni = 0; ni < 4; ++ni)
          acc[mi][ni] = __builtin_amdgcn_mfma_f32_16x16x32_bf16(
              af[mi], bf[ni], acc[mi][ni], 0, 0, 0);
      __builtin_amdgcn_s_setprio(0);
    }
    // ---- phase 1 (mh=1): stage B(t+2); read af[4..7]; 16 MFMA ----
    __builtin_amdgcn_s_barrier();
    CFENCE;
    if (st) {
#pragma unroll
      for (int i = 0; i < 2; ++i)
        gll16(Bw + b_base + ab_off[i] + (t + 2) * 32, &sm[ws][8192 + dstc[i]]);
    }
    {
      bf16x8 af[4];
#pragma unroll
      for (int mi = 0; mi < 4; ++mi) {
        int r = arow[4 + mi];
        af[mi] = *(const bf16x8*)&As[r * 32 + ((q ^ (r & 3)) << 3)];
      }
      __builtin_amdgcn_s_setprio(1);
#pragma unroll
      for (int mi = 0; mi < 4; ++mi)
#pragma unroll
        for (int ni = 0; ni < 4; ++ni)
          acc[4 + mi][ni] = __builtin_amdgcn_mfma_f32_16x16x32_bf16(
              af[mi], bf[ni], acc[4 + mi][ni], 0, 0, 0);
      __builtin_amdgcn_s_setprio(0);
    }
  }

  // ---- epilogue ----
  long crow0 = (long)ty * 256 + wm * 128;
  long ccol0 = (long)tx * 256 + wn * 64;
#pragma unroll
  for (int mi = 0; mi < 8; ++mi) {
#pragma unroll
    for (int ni = 0; ni < 4; ++ni) {
      long col = ccol0 + ni * 16 + l15;
      float bv = bias[col];
#pragma unroll
      for (int j = 0; j < 4; ++j) {
        long row = crow0 + mi * 16 + (q << 2) + j;
        Cb[row * N + col] = f2b(acc[mi][ni][j] + bv);
      }
    }
  }
}

// -------------------- GEMM (fallback path): 128x128 m97-style ---------
#define BM 128
#define BN 128
#define BKS 64

template<int OUTBF>
__global__ __launch_bounds__(256)
void gemm_bt(const unsigned short* __restrict__ A,
             const unsigned short* __restrict__ Bw,
             const float* __restrict__ bias,
             float* __restrict__ Cf, unsigned short* __restrict__ Cb,
             int M, int N, int K)
{
  __shared__ __align__(16) unsigned short As[BM * BKS];
  __shared__ __align__(16) unsigned short Bs[BN * BKS];

  int nwg = gridDim.x * gridDim.y;
  int wg = blockIdx.y * gridDim.x + blockIdx.x;
  if ((nwg & 7) == 0) { int ch = nwg >> 3; wg = (wg & 7) * ch + (wg >> 3); }
  int tx = wg % gridDim.x;
  int ty = wg / gridDim.x;

  const int tid = threadIdx.x;
  const int lane = tid & 63;
  const int wave = tid >> 6;
  const int wr = wave >> 1, wc = wave & 1;

  f32x4 acc[4][4] = {};

  const long a_base = (long)ty * BM * K;
  const long b_base = (long)tx * BN * K;

  for (int kt = 0; kt < K; kt += BKS) {
    __syncthreads();
#pragma unroll
    for (int i = 0; i < 4; ++i) {
      int c = i * 256 + tid;
      int row = c >> 3, sc = c & 7;
      int gcol8 = sc ^ (row & 7);
      const unsigned short* ga = A + a_base + (long)row * K + kt + gcol8 * 8;
      const unsigned short* gb = Bw + b_base + (long)row * K + kt + gcol8 * 8;
      int cbase = (i * 256 + wave * 64) * 8;
      gll16(ga, &As[cbase]);
      gll16(gb, &Bs[cbase]);
    }
    __syncthreads();
#pragma unroll
    for (int kk = 0; kk < BKS; kk += 32) {
      int kidx = kk + ((lane >> 4) << 3);
      int c8 = kidx >> 3;
      bf16x8 af[4], bfv[4];
#pragma unroll
      for (int m = 0; m < 4; ++m) {
        int row = wr * 64 + m * 16 + (lane & 15);
        af[m] = *(const bf16x8*)&As[row * BKS + ((c8 ^ (row & 7)) << 3)];
      }
#pragma unroll
      for (int n = 0; n < 4; ++n) {
        int col = wc * 64 + n * 16 + (lane & 15);
        bfv[n] = *(const bf16x8*)&Bs[col * BKS + ((c8 ^ (col & 7)) << 3)];
      }
#pragma unroll
      for (int m = 0; m < 4; ++m)
#pragma unroll
        for (int n = 0; n < 4; ++n)
          acc[m][n] = __builtin_amdgcn_mfma_f32_16x16x32_bf16(
              af[m], bfv[n], acc[m][n], 0, 0, 0);
    }
  }

  long crow0 = (long)ty * BM + wr * 64;
  long ccol0 = (long)tx * BN + wc * 64;
#pragma unroll
  for (int m = 0; m < 4; ++m) {
#pragma unroll
    for (int n = 0; n < 4; ++n) {
      long col = ccol0 + n * 16 + (lane & 15);
      float bv = bias[col];
#pragma unroll
      for (int j = 0; j < 4; ++j) {
        long row = crow0 + m * 16 + ((lane >> 4) << 2) + j;
        float v = acc[m][n][j] + bv;
        if (OUTBF) Cb[row * N + col] = f2b(v);
        else       Cf[row * N + col] = v;
      }
    }
  }
}

// -------------------- persistent fused recurrence v4 (R7/R9 verbatim) -
__global__ __launch_bounds__(512, 1)
void gru_rec4(const unsigned short* __restrict__ GI,
              const unsigned short* __restrict__ Whp,
              const float* __restrict__ bhp,
              const unsigned short* __restrict__ h0,
              unsigned short* __restrict__ hbuf0,
              unsigned short* __restrict__ hbuf1,
              unsigned short* __restrict__ Y,
              unsigned int* __restrict__ bar,
              int B, int E, int K, int net)
{
  __shared__ __align__(16) unsigned char smem[156672];     // 153 KB
  unsigned short* Ah  = (unsigned short*)smem;             // 6 x 8KB A ring
  unsigned short* Bss = (unsigned short*)(smem + 49152);   // 3 x 24KB B ring
  unsigned short* GIs = (unsigned short*)(smem + 122880);  // 24KB
  unsigned short* Ys  = (unsigned short*)(smem + 147456);  // 9KB persistent h
  float* Red = (float*)smem;  // gate-phase alias over dead A/B-head space

  const int N3 = 3 * E;
  const int e6 = blockIdx.x;           // e6%8 -> XCD pinning of Whh panel
  const int bt = blockIdx.y;
  const int b0 = bt << 6;
  const int ec0 = e6 * 192;
  const int ecol0 = e6 << 6;
  const int tid = threadIdx.x;
  const int lane = tid & 63;
  const int w = tid >> 6;
  const int ew = w >> 1;               // e-col group (16 cols)
  const int kw = w & 1;                // K-half
  const int q = lane >> 4;
  const int l15 = lane & 15;
  const int el = (ew << 4) + l15;
  const int c8 = (kw << 2) + q;
  const int axo = (c8 ^ (l15 & 7)) << 3;
  const int bxo = (c8 ^ (el & 7)) << 3;

  const int arow = tid >> 3;
  const int ag8 = (tid & 7) ^ (arow & 7);
  const long a_goff = (long)(b0 + arow) * E + ag8 * 8;
  const int a_dst = tid * 8;
  long b_goff[3]; int b_dst[3];
#pragma unroll
  for (int i = 0; i < 3; ++i) {
    int c = i * 512 + tid;
    int row = c >> 3;
    int g8 = (c & 7) ^ (row & 7);
    b_goff[i] = (long)(ec0 + row) * E + g8 * 8;
    b_dst[i] = c * 8;
  }
  long gi_off[3]; int gi_dst[3];
#pragma unroll
  for (int i = 0; i < 3; ++i) {
    int c = i * 512 + tid;
    int row = c / 24, cc = c - row * 24;
    gi_off[i] = (long)(b0 + row) * N3 + ec0 + cc * 8;
    gi_dst[i] = c * 8;
  }

  const float bh0 = bhp[ec0 + el];
  const float bh1 = bhp[ec0 + 64 + el];
  const float bh2 = bhp[ec0 + 128 + el];

  if (kw == 0) {
#pragma unroll
    for (int m = 0; m < 4; ++m)
#pragma unroll
      for (int j = 0; j < 4; ++j) {
        int row = m * 16 + q * 4 + j;
        Ys[row * 72 + el] = h0[(long)(b0 + row) * E + ecol0 + el];
      }
  }
  __syncthreads();

  for (int k = 0; k < K; ++k) {
    const unsigned short* hprev = (k & 1) ? hbuf1 : hbuf0;
    unsigned short* hnext = (k & 1) ? hbuf0 : hbuf1;
    const unsigned short* GIk = GI + (long)k * B * N3;

    // ---- prolog issue: GI(3), A tiles 0..4 (coherent), B tiles 0,1 ----
#pragma unroll
    for (int i = 0; i < 3; ++i) gll16(GIk + gi_off[i], GIs + gi_dst[i]);
#pragma unroll
    for (int t = 0; t < 5; ++t)
      gll16u(hprev + a_goff + t * 64, Ah + t * 4096 + a_dst);
#pragma unroll
    for (int t = 0; t < 2; ++t)
#pragma unroll
      for (int i = 0; i < 3; ++i)
        gll16(Whp + b_goff[i] + t * 64, Bss + t * 12288 + b_dst[i]);

    f32x4 acc[4][3];
#pragma unroll
    for (int m = 0; m < 4; ++m)
#pragma unroll
      for (int g = 0; g < 3; ++g)
        acc[m][g] = (f32x4){0.f, 0.f, 0.f, 0.f};

#pragma unroll
    for (int kt = 0; kt < 16; ++kt) {
      if (kt == 0)       VMW(3);
      else if (kt == 1)  VMW(4);
      else if (kt <= 11) VMW(5);
      else if (kt == 12) VMW(4);
      else if (kt == 15) VMW(0);
      else               VMW(3);
      LGKM0;
      __builtin_amdgcn_s_barrier();
      CFENCE;

      if (kt + 2 < 16) {
#pragma unroll
        for (int i = 0; i < 3; ++i)
          gll16(Whp + b_goff[i] + (kt + 2) * 64,
                Bss + ((kt + 2) % 3) * 12288 + b_dst[i]);
      }
      if (kt + 5 < 16)
        gll16u(hprev + a_goff + (kt + 5) * 64,
               Ah + ((kt + 5) % 6) * 4096 + a_dst);

      const unsigned short* Ab = Ah + (kt % 6) * 4096;
      const unsigned short* Bb = Bss + (kt % 3) * 12288;
      bf16x8 af[4], bfg[3];
#pragma unroll
      for (int m = 0; m < 4; ++m)
        af[m] = *(const bf16x8*)&Ab[(m * 16 + l15) * 64 + axo];
#pragma unroll
      for (int g = 0; g < 3; ++g)
        bfg[g] = *(const bf16x8*)&Bb[(g * 64 + el) * 64 + bxo];

      __builtin_amdgcn_s_setprio(1);
#pragma unroll
      for (int g = 0; g < 3; ++g)
#pragma unroll
        for (int m = 0; m < 4; ++m)
          acc[m][g] = __builtin_amdgcn_mfma_f32_16x16x32_bf16(
              af[m], bfg[g], acc[m][g], 0, 0, 0);
      __builtin_amdgcn_s_setprio(0);
    }

    // ---- K-split reduce (Red aliases dead A/B LDS) + fused gates ----
    __syncthreads();
    float* rp = &Red[((ew << 6) + lane) * 49];
    if (kw == 1) {
#pragma unroll
      for (int m = 0; m < 4; ++m)
#pragma unroll
        for (int g = 0; g < 3; ++g)
#pragma unroll
          for (int cc = 0; cc < 4; ++cc)
            rp[(m * 3 + g) * 4 + cc] = acc[m][g][cc];
    }
    __syncthreads();
    if (kw == 0) {
#pragma unroll
      for (int m = 0; m < 4; ++m) {
#pragma unroll
        for (int j = 0; j < 4; ++j) {
          int row = m * 16 + q * 4 + j;
          float ghr = acc[m][0][j] + rp[(m * 3 + 0) * 4 + j];
          float ghz = acc[m][1][j] + rp[(m * 3 + 1) * 4 + j];
          float ghn = acc[m][2][j] + rp[(m * 3 + 2) * 4 + j];
          float gr = b2f(GIs[row * 192 + el]);
          float gz = b2f(GIs[row * 192 + 64 + el]);
          float gn = b2f(GIs[row * 192 + 128 + el]);
          float hu = b2f(Ys[row * 72 + el]);
          float r = sigm(gr + ghr + bh0);
          float z = sigm(gz + ghz + bh1);
          float n = tanh_f(gn + r * (ghn + bh2));
          float hv = (1.f - z) * n + z * hu;
          Ys[row * 72 + el] = f2b(hv);
        }
      }
    }
    __syncthreads();
    {
      int row = tid >> 3, cc = tid & 7;
      u16x8 v = *(const u16x8*)&Ys[row * 72 + cc * 8];
      unsigned* pv = (unsigned*)&v;
      unsigned long long s0 = ((unsigned long long)pv[1] << 32) | pv[0];
      unsigned long long s1 = ((unsigned long long)pv[3] << 32) | pv[2];
      unsigned short* hp = hnext + (long)(b0 + row) * E + ecol0 + cc * 8;
      as64(hp, s0);
      as64(hp + 4, s1);
      *(u16x8*)(Y + ((long)k * B + b0 + row) * E + ecol0 + cc * 8) = v;
    }
    if (k + 1 < K) {
      __syncthreads();
      if (tid == 0) {
        __hip_atomic_fetch_add(&bar[bt * 64], 1u, __ATOMIC_RELAXED,
                               __HIP_MEMORY_SCOPE_AGENT);
        unsigned target = (unsigned)(k + 1) * (unsigned)net;
        while (__hip_atomic_load(&bar[bt * 64], __ATOMIC_RELAXED,
                                 __HIP_MEMORY_SCOPE_AGENT) < target)
          __builtin_amdgcn_s_sleep(1);
      }
      __syncthreads();
    }
  }
}

// -------------------- pointwise GRU gates (fallback path) -------------
template<int YMODE>
__global__ __launch_bounds__(256)
void gru_pointwise(const unsigned short* __restrict__ GIk,
                   const float* __restrict__ gh,
                   float* __restrict__ h, unsigned short* __restrict__ hbf,
                   unsigned short* __restrict__ Yb,
                   float* __restrict__ out, int k, int B, int E, int K)
{
  long i4 = ((long)blockIdx.x * blockDim.x + threadIdx.x) * 4;
  if (i4 >= (long)B * E) return;
  long b = i4 / E;
  long e = i4 - b * E;
  long g0 = b * 3 * E + e;
  ushort4 ir = *(const ushort4*)(GIk + g0);
  ushort4 iz = *(const ushort4*)(GIk + g0 + E);
  ushort4 in4 = *(const ushort4*)(GIk + g0 + 2 * E);
  float4 hr = *(const float4*)(gh + g0);
  float4 hz = *(const float4*)(gh + g0 + E);
  float4 hn = *(const float4*)(gh + g0 + 2 * E);
  float4 hv = *(const float4*)(h + i4);

  float irf[4] = { b2f(ir.x), b2f(ir.y), b2f(ir.z), b2f(ir.w) };
  float izf[4] = { b2f(iz.x), b2f(iz.y), b2f(iz.z), b2f(iz.w) };
  float inf_[4] = { b2f(in4.x), b2f(in4.y), b2f(in4.z), b2f(in4.w) };
  float hrf[4] = { hr.x, hr.y, hr.z, hr.w };
  float hzf[4] = { hz.x, hz.y, hz.z, hz.w };
  float hnf[4] = { hn.x, hn.y, hn.z, hn.w };
  float hvf[4] = { hv.x, hv.y, hv.z, hv.w };
  float hnew[4];
#pragma unroll
  for (int j = 0; j < 4; ++j) {
    float r = sigm(irf[j] + hrf[j]);
    float z = sigm(izf[j] + hzf[j]);
    float n = tanh_f(inf_[j] + r * hnf[j]);
    hnew[j] = (1.f - z) * n + z * hvf[j];
  }
  *(float4*)(h + i4) = make_float4(hnew[0], hnew[1], hnew[2], hnew[3]);
  ushort4 hb = make_ushort4(f2b(hnew[0]), f2b(hnew[1]), f2b(hnew[2]), f2b(hnew[3]));
  *(ushort4*)(hbf + i4) = hb;
  if (YMODE == 1) {
    *(ushort4*)(Yb + ((long)k * B + b) * E + e) = hb;
  } else {
    float* o = out + (b * E + e) * K + k;
    o[0] = hnew[0]; o[K] = hnew[1]; o[2 * K] = hnew[2]; o[3 * K] = hnew[3];
  }
}

// -------------------- transpose Y (K,B,E) bf16 -> out (B,E,K) fp32 ----
__global__ __launch_bounds__(256)
void transpose_y(const unsigned short* __restrict__ Yv, float* __restrict__ out,
                 int B, int E, int K)
{
  __shared__ float T[64][65];
  int e0 = blockIdx.x * 64;
  int b = blockIdx.y;
  int t = threadIdx.x;
#pragma unroll
  for (int i = 0; i < 4; ++i) {
    int c = i * 256 + t;
    int k = c >> 4, f4 = c & 15;
    long off = ((long)k * B + b) * E + e0 + f4 * 4;
    ushort4 v = *(const ushort4*)(Yv + off);
    T[k][f4 * 4 + 0] = b2f(v.x); T[k][f4 * 4 + 1] = b2f(v.y);
    T[k][f4 * 4 + 2] = b2f(v.z); T[k][f4 * 4 + 3] = b2f(v.w);
  }
  __syncthreads();
#pragma unroll
  for (int i = 0; i < 4; ++i) {
    int c = i * 256 + t;
    int e = c >> 4, f4k = c & 15;
    float4 w;
    w.x = T[f4k * 4 + 0][e];
    w.y = T[f4k * 4 + 1][e];
    w.z = T[f4k * 4 + 2][e];
    w.w = T[f4k * 4 + 3][e];
    *(float4*)(out + ((long)b * E + e0 + e) * K + f4k * 4) = w;
  }
}

// -------------------- host launch -------------------------------------
extern "C" void kernel_launch(void* const* d_in, const int* in_sizes, int n_in,
                              void* d_out, int out_size, void* d_ws, size_t ws_size,
                              hipStream_t stream)
{
  const float* c   = (const float*)d_in[0];
  const float* x   = (const float*)d_in[1];
  const float* Wih = (const float*)d_in[2];
  const float* Whh = (const float*)d_in[3];
  const float* bih = (const float*)d_in[4];
  const float* bhh = (const float*)d_in[5];
  float* out = (float*)d_out;

  long BE = in_sizes[0];
  int E = (int)(sqrtf((float)(in_sizes[2] / 3)) + 0.5f);
  int B = (int)(BE / E);
  int K = (int)(in_sizes[1] / BE);
  int N3 = 3 * E;
  long M_GI = (long)K * B;

  char* w = (char*)d_ws;
  size_t used = 0;
  auto alloc = [&](size_t bytes) -> char* {
    char* p = w + used;
    used += (bytes + 255) & ~(size_t)255;
    return p;
  };
  unsigned short* XS = (unsigned short*)alloc((size_t)K * B * E * 2);

  size_t szW   = (((size_t)N3 * E * 2) + 255) & ~(size_t)255;
  size_t szB3  = (((size_t)N3 * 4) + 255) & ~(size_t)255;
  size_t szHb  = (((size_t)B * E * 2) + 255) & ~(size_t)255;
  size_t szGI  = (((size_t)K * B * N3 * 2) + 255) & ~(size_t)255;
  size_t szY   = (((size_t)K * B * E * 2) + 255) & ~(size_t)255;
  int nbt = B / 64, net = E / 64;
  size_t szBar = ((size_t)nbt * 64 * 4 + 255) & ~(size_t)255;

  size_t needFused = 2 * szW + 2 * szB3 + 2 * szHb + szGI + szY + szBar;
  bool canFused = (B == 1024) && (E == 1024) && (K == 64) &&
                  (ws_size > used) && ((ws_size - used) >= needFused);

  if (canFused) {
    unsigned short* Wihp = (unsigned short*)alloc(szW);
    unsigned short* Whhp = (unsigned short*)alloc(szW);
    float* bihp          = (float*)alloc(szB3);
    float* bhhp          = (float*)alloc(szB3);
    unsigned short* hb0  = (unsigned short*)alloc(szHb);
    unsigned short* hb1  = (unsigned short*)alloc(szHb);
    unsigned short* GI   = (unsigned short*)alloc(szGI);
    unsigned short* Yb   = (unsigned short*)alloc(szY);
    unsigned int*   bar  = (unsigned int*)alloc(szBar);

    prep2_kernel<<<dim3(2048), dim3(256), 0, stream>>>(
        Wih, Whh, c, bih, bhh, Wihp, Whhp, bihp, bhhp, hb0, E, BE);
    hipMemsetAsync(XS, 0, (size_t)B * E * 2, stream);
    transpose_x<<<dim3(E / 64, B), dim3(256), 0, stream>>>(x, XS, B, E, K);

    // GI GEMM: M=65536 (256-tiles), N=3072 (256-tiles), K=1024
    gemm256k32<<<dim3(N3 / 256, (int)(M_GI / 256)), dim3(512), 0, stream>>>(
        XS, Wihp, bihp, GI, (int)M_GI, N3, E);
    hipMemsetAsync(bar, 0, szBar, stream);

    const unsigned short* GIc = GI;
    const unsigned short* Whhc = Whhp;
    const float* bhhc = bhhp;
    const unsigned short* h0c = hb0;
    void* args[] = { (void*)&GIc, (void*)&Whhc, (void*)&bhhc, (void*)&h0c,
                     (void*)&hb0, (void*)&hb1, (void*)&Yb,
                     (void*)&bar, (void*)&B, (void*)&E, (void*)&K, (void*)&net };
    hipError_t ce = hipLaunchCooperativeKernel(
        (const void*)gru_rec4, dim3(net, nbt), dim3(512), args, 0, stream);
    if (ce != hipSuccess) {
      (void)hipGetLastError();
      gru_rec4<<<dim3(net, nbt), dim3(512), 0, stream>>>(
          GIc, Whhc, bhhc, h0c, hb0, hb1, Yb, bar, B, E, K, net);
    }
    transpose_y<<<dim3(E / 64, B), dim3(256), 0, stream>>>(Yb, out, B, E, K);
    return;
  }

  // -------- fallback: per-step GEMMs (round-1 path, normal layout) -----
  unsigned short* Wihb  = (unsigned short*)alloc(szW);
  unsigned short* Whhb  = (unsigned short*)alloc(szW);
  unsigned short* hb0   = (unsigned short*)alloc(szHb);
  float* h32            = (float*)alloc((size_t)B * E * 4);
  float* gh             = (float*)alloc((size_t)B * N3 * 4);
  unsigned short* GIstep= (unsigned short*)alloc((size_t)B * N3 * 2);
  size_t rem = (ws_size > used) ? ws_size - used : 0;
  int haveY = rem >= szY;
  unsigned short* Yb = haveY ? (unsigned short*)alloc(szY) : nullptr;

  long nW = (long)N3 * E;
  prep_kernel<<<dim3(2048), dim3(256), 0, stream>>>(Wih, Whh, c, Wihb, Whhb,
                                                    hb0, h32, nW, BE);
  hipMemsetAsync(XS, 0, (size_t)B * E * 2, stream);
  transpose_x<<<dim3(E / 64, B), dim3(256), 0, stream>>>(x, XS, B, E, K);

  int pgrid = (int)((BE / 4 + 255) / 256);
  for (int k = 0; k < K; ++k) {
    gemm_bt<1><<<dim3(N3 / BN, B / BM), dim3(256), 0, stream>>>(
        XS + (size_t)k * B * E, Wihb, bih, nullptr, GIstep, B, N3, E);
    gemm_bt<0><<<dim3(N3 / BN, B / BM), dim3(256), 0, stream>>>(
        hb0, Whhb, bhh, gh, nullptr, B, N3, E);
    if (haveY)
      gru_pointwise<1><<<dim3(pgrid), dim3(256), 0, stream>>>(
          GIstep, gh, h32, hb0, Yb, out, k, B, E, K);
    else
      gru_pointwise<2><<<dim3(pgrid), dim3(256), 0, stream>>>(
          GIstep, gh, h32, hb0, nullptr, out, k, B, E, K);
  }
  if (haveY)
    transpose_y<<<dim3(E / 64, B), dim3(256), 0, stream>>>(Yb, out, B, E, K);
}